// Round 4
// baseline (43209.360 us; speedup 1.0000x reference)
//
#include <hip/hip_runtime.h>
#include <math.h>

// GRANCascadingPredictor — dtype-adaptive, ws-adaptive, fp32-compute.
//
// DTYPE: unknown whether float tensors are fp32 or bf16 on device. A device
// probe (detect_k) reads ent_emb as bf16 pairs: true-bf16 data -> all small;
// fp32-as-bf16 -> mantissa halves have random exponents -> huge. Flag in ws
// drives: weight conversion to fp32 arena, gather/text loads, output store.
//
// Round-3 zero-output mechanism (solved): fp32 inputs read as bf16 -> inf
// state -> inf-inf=NaN -> fmaxf(NaN,0)=0 at head relu -> out = bias = 0.
//
// Structure: B disjoint 4-node stars. src(e)=e<2B?e:e-B, dst(e)=e+Bn.
// agg has no collisions. Edge one-hot folded into per-type bias row.
// GRU processed DESCENDING over node chunks (C,B,Event,A): edges into chunk r
// read only chunk r-1 (not yet updated) and chunk r pre-update -> no full-P
// buffer needed; everything runs in RC=2048-row chunks through a 32MB arena.
//
// ws: [flag 256B][weights fp32 21.4MB][arena 33.5MB][state 4B*512*esz]
//   big path (ws >= 189,183,360): fp32 state — bit-faithful to fp32 ref.
//   small path: bf16 state (64MB) — ~0.3% drift vs 2% threshold.

#define Bn 16384
#define Hn 512
#define Dn 256
#define Tn 768
#define RC 2048

#define EPI_NONE 0
#define EPI_RELU 1
#define EPI_SIG_MUL 2
#define EPI_RELU_GATHER 3

typedef unsigned short bfu;

// weight-arena offsets (floats), all 16B-aligned
#define OFF_TEXTW 0
#define OFF_TEXTB 196608
#define OFF_PROJW 196864
#define OFF_PROJB 327936
#define OFF_MSGW1 328448
#define OFF_MSGB1 860928
#define OFF_MSGW2 861952
#define OFF_MSGB2 1386240
#define OFF_ATTW1 1387264
#define OFF_ATTB1 1653504
#define OFF_ATTW2 1654016
#define OFF_ATTB2 1916160
#define OFF_GWIH 1917184
#define OFF_GWHH 3490048
#define OFF_GBIH 5062912
#define OFF_GBHH 5065984
#define OFF_HW1 5069056
#define OFF_HB1 5331200
#define OFF_HW2 5331712
#define OFF_HB2 5348096
#define OFF_BTM 5348128
#define OFF_BTA 5351200
#define WF_TOTAL 5352736

__device__ __forceinline__ float sigf(float x) { return 1.f / (1.f + expf(-x)); }

__device__ __forceinline__ float b2f(bfu v) {
  union { unsigned q; float f; } c;
  c.q = (unsigned)v << 16;
  return c.f;
}

__device__ __forceinline__ float4 bf4(uint2 u) {
  union { unsigned q; float f; } c;
  float4 r;
  c.q = u.x << 16;          r.x = c.f;
  c.q = u.x & 0xFFFF0000u;  r.y = c.f;
  c.q = u.y << 16;          r.z = c.f;
  c.q = u.y & 0xFFFF0000u;  r.w = c.f;
  return r;
}

__device__ __forceinline__ unsigned f2bu(float x) {
  union { float f; unsigned u; } c;
  c.f = x;
  return (c.u + 0x7FFFu + ((c.u >> 16) & 1u)) >> 16;
}
__device__ __forceinline__ uint2 f2b4(float4 v) {
  uint2 r;
  r.x = f2bu(v.x) | (f2bu(v.y) << 16);
  r.y = f2bu(v.z) | (f2bu(v.w) << 16);
  return r;
}

// flag=1 -> inputs are bf16; flag=0 -> fp32.
__global__ void detect_k(const unsigned* __restrict__ p, int* __restrict__ flag) {
  __shared__ float red[256];
  const int t = threadIdx.x;
  union { unsigned q; float f; } c;
  c.q = p[t] << 16;  // low 16 bits interpreted as bf16
  float m = fabsf(c.f);
  if (!(m == m)) m = 1e30f;  // NaN -> huge
  red[t] = m;
  __syncthreads();
  for (int s = 128; s > 0; s >>= 1) {
    if (t < s) red[t] = fmaxf(red[t], red[t + s]);
    __syncthreads();
  }
  if (t == 0) flag[0] = (red[0] < 1e3f) ? 1 : 0;
}

__global__ void convert_k(const void* __restrict__ src, float* __restrict__ dst,
                          int n, const int* __restrict__ flagp) {
  const int i = blockIdx.x * blockDim.x + threadIdx.x;
  if (i >= n) return;
  dst[i] = flagp[0] ? b2f(((const bfu*)src)[i]) : ((const float*)src)[i];
}

// out = b[i%N] + wr[i], fp32 (per-edge-type folded bias)
__global__ void build_btype_k(const float* __restrict__ b, const float* __restrict__ wr,
                              float* __restrict__ out, int N) {
  const int i = blockIdx.x * blockDim.x + threadIdx.x;
  if (i < 3 * N) out[i] = b[i % N] + wr[i];
}

// Xc[r] = ent_emb[ids[r]] -> fp32. one row/block, 64 threads x 4 elems.
__global__ void gather_k(const int* __restrict__ ids, const void* __restrict__ emb,
                         float* __restrict__ Xc, const int* __restrict__ flagp) {
  const int r = blockIdx.x, t = threadIdx.x;
  const int id = ids[r];
  float4 v;
  if (flagp[0])
    v = bf4(((const uint2*)((const bfu*)emb + (size_t)id * Dn))[t]);
  else
    v = ((const float4*)((const float*)emb + (size_t)id * Dn))[t];
  ((float4*)(Xc + (size_t)r * Dn))[t] = v;
}

// C[M,N] = epi(A[M,K] @ W + bias). fp32 accumulate, 128x128x8 tile, 8x8/thread.
// W, bias, extra always fp32 (converted arena). BT=0: W[K,N]; BT=1: W[N,K].
// AM: 0=A fp32 local rows; 1=A flag-dtyped global input, rows rowOff+row;
//     2/3 = A row e=rowOff+row -> state[src(e)]-state[e+Bn], state fp32/bf16;
//     4 = A bf16 local rows (bf16 state chunk).
// CT: 0=C fp32; 1=C bf16.
// EPI_SIG_MUL: C = sigmoid(acc+bias)*extra (fp32, may alias C elementwise).
// EPI_RELU_GATHER: C = relu(acc+bias) + gtab[gidx[rowOff+row]*N + n] (flag dtype).
template <int EPI, int BT, int AM, int CT>
__global__ __launch_bounds__(256, 2) void sgemm_k(
    const void* __restrict__ Ap, const float* __restrict__ W,
    const float* __restrict__ bias, const float* __restrict__ extra,
    const int* __restrict__ gidx, const void* __restrict__ gtab,
    void* __restrict__ C, int M, int N, int K, int rowOff,
    const int* __restrict__ flagp) {
  __shared__ __align__(16) float As[8][128];
  __shared__ __align__(16) float Bs[8][128];
  const int t = threadIdx.x;
  const int row0 = blockIdx.y * 128;
  const int col0 = blockIdx.x * 128;
  const int tx = t & 15, ty = t >> 4;
  const int arow = t >> 1;
  const int akof = (t & 1) * 4;
  const int wk = t >> 5;
  const int wn = (t & 31) * 4;
  const int fl = (AM == 1 || EPI == EPI_RELU_GATHER) ? flagp[0] : 0;

  float acc[8][8];
#pragma unroll
  for (int i = 0; i < 8; ++i)
#pragma unroll
    for (int j = 0; j < 8; ++j) acc[i][j] = 0.f;

  auto loadA = [&](int k) -> float4 {
    if (AM == 0) {
      return *(const float4*)((const float*)Ap + (size_t)(row0 + arow) * K + k + akof);
    } else if (AM == 1) {
      const size_t off = (size_t)(rowOff + row0 + arow) * K + k + akof;
      if (fl) return bf4(*(const uint2*)((const bfu*)Ap + off));
      return *(const float4*)((const float*)Ap + off);
    } else if (AM == 4) {
      return bf4(*(const uint2*)((const bfu*)Ap + (size_t)(row0 + arow) * K + k + akof));
    } else {
      const int e = rowOff + row0 + arow;
      const int s = (e < 2 * Bn) ? e : e - Bn;
      float4 x, y;
      if (AM == 2) {
        const float* st = (const float*)Ap;
        x = *(const float4*)(st + (size_t)s * Hn + k + akof);
        y = *(const float4*)(st + (size_t)(e + Bn) * Hn + k + akof);
      } else {
        const bfu* st = (const bfu*)Ap;
        x = bf4(*(const uint2*)(st + (size_t)s * Hn + k + akof));
        y = bf4(*(const uint2*)(st + (size_t)(e + Bn) * Hn + k + akof));
      }
      return make_float4(x.x - y.x, x.y - y.y, x.z - y.z, x.w - y.w);
    }
  };
  auto loadW = [&](int k) -> float4 {
    if (BT == 0)
      return *(const float4*)(W + (size_t)(k + wk) * N + col0 + wn);
    else
      return *(const float4*)(W + (size_t)(col0 + arow) * K + k + akof);
  };

  float4 aReg = loadA(0);
  float4 wReg = loadW(0);

  int k0 = 0;
  while (true) {
    __syncthreads();
    As[akof + 0][arow] = aReg.x;
    As[akof + 1][arow] = aReg.y;
    As[akof + 2][arow] = aReg.z;
    As[akof + 3][arow] = aReg.w;
    if (BT == 0) {
      *(float4*)(&Bs[wk][wn]) = wReg;
    } else {
      Bs[akof + 0][arow] = wReg.x;
      Bs[akof + 1][arow] = wReg.y;
      Bs[akof + 2][arow] = wReg.z;
      Bs[akof + 3][arow] = wReg.w;
    }
    __syncthreads();
    const int knext = k0 + 8;
    if (knext < K) {
      aReg = loadA(knext);
      wReg = loadW(knext);
    }
#pragma unroll
    for (int k = 0; k < 8; ++k) {
      float4 a0 = *(const float4*)(&As[k][ty * 8]);
      float4 a1 = *(const float4*)(&As[k][ty * 8 + 4]);
      float4 b0 = *(const float4*)(&Bs[k][tx * 4]);
      float4 b1 = *(const float4*)(&Bs[k][64 + tx * 4]);
      float av[8] = {a0.x, a0.y, a0.z, a0.w, a1.x, a1.y, a1.z, a1.w};
      float bv[8] = {b0.x, b0.y, b0.z, b0.w, b1.x, b1.y, b1.z, b1.w};
#pragma unroll
      for (int i = 0; i < 8; ++i)
#pragma unroll
        for (int j = 0; j < 8; ++j) acc[i][j] = fmaf(av[i], bv[j], acc[i][j]);
    }
    if (knext >= K) break;
    k0 = knext;
  }

  const int c0 = col0 + tx * 4;
  const int c1 = col0 + 64 + tx * 4;
  float4 bb0 = *(const float4*)(bias + c0);
  float4 bb1 = *(const float4*)(bias + c1);

#pragma unroll
  for (int i = 0; i < 8; ++i) {
    const int row = row0 + ty * 8 + i;
    float4 v0, v1;
    v0.x = acc[i][0] + bb0.x; v0.y = acc[i][1] + bb0.y;
    v0.z = acc[i][2] + bb0.z; v0.w = acc[i][3] + bb0.w;
    v1.x = acc[i][4] + bb1.x; v1.y = acc[i][5] + bb1.y;
    v1.z = acc[i][6] + bb1.z; v1.w = acc[i][7] + bb1.w;
    if (EPI == EPI_RELU || EPI == EPI_RELU_GATHER) {
      v0.x = fmaxf(v0.x, 0.f); v0.y = fmaxf(v0.y, 0.f);
      v0.z = fmaxf(v0.z, 0.f); v0.w = fmaxf(v0.w, 0.f);
      v1.x = fmaxf(v1.x, 0.f); v1.y = fmaxf(v1.y, 0.f);
      v1.z = fmaxf(v1.z, 0.f); v1.w = fmaxf(v1.w, 0.f);
    }
    if (EPI == EPI_SIG_MUL) {
      const float* ep = extra + (size_t)row * N;
      float4 e0 = *(const float4*)(ep + c0);
      float4 e1 = *(const float4*)(ep + c1);
      v0.x = sigf(v0.x) * e0.x; v0.y = sigf(v0.y) * e0.y;
      v0.z = sigf(v0.z) * e0.z; v0.w = sigf(v0.w) * e0.w;
      v1.x = sigf(v1.x) * e1.x; v1.y = sigf(v1.y) * e1.y;
      v1.z = sigf(v1.z) * e1.z; v1.w = sigf(v1.w) * e1.w;
    }
    if (EPI == EPI_RELU_GATHER) {
      const int grow = gidx[rowOff + row];
      float4 g0, g1;
      if (fl) {
        const bfu* g = (const bfu*)gtab + (size_t)grow * N;
        g0 = bf4(*(const uint2*)(g + c0));
        g1 = bf4(*(const uint2*)(g + c1));
      } else {
        const float* g = (const float*)gtab + (size_t)grow * N;
        g0 = *(const float4*)(g + c0);
        g1 = *(const float4*)(g + c1);
      }
      v0.x += g0.x; v0.y += g0.y; v0.z += g0.z; v0.w += g0.w;
      v1.x += g1.x; v1.y += g1.y; v1.z += g1.z; v1.w += g1.w;
    }
    if (CT == 0) {
      float* cp = (float*)C + (size_t)row * N;
      *(float4*)(cp + c0) = v0;
      *(float4*)(cp + c1) = v1;
    } else {
      bfu* cp = (bfu*)C + (size_t)row * N;
      *(uint2*)(cp + c0) = f2b4(v0);
      *(uint2*)(cp + c1) = f2b4(v1);
    }
  }
}

// GRU gate for one RC-row chunk. gi==nullptr -> agg==0 chunk: gi = bih (fp32).
template <int ST>
__global__ void gru_gate_k(const float* __restrict__ gi, const float* __restrict__ bih,
                           const float* __restrict__ gh, void* __restrict__ state_c) {
  const int idx = blockIdx.x * blockDim.x + threadIdx.x;
  const int m = idx >> 7;
  const int c = (idx & 127) << 2;
  const float* gp = gh + (size_t)m * (3 * Hn);
  float4 hr = *(const float4*)(gp + c);
  float4 hz = *(const float4*)(gp + Hn + c);
  float4 hn = *(const float4*)(gp + 2 * Hn + c);
  float4 ir, iz, inn;
  if (gi) {
    const float* ip = gi + (size_t)m * (3 * Hn);
    ir = *(const float4*)(ip + c);
    iz = *(const float4*)(ip + Hn + c);
    inn = *(const float4*)(ip + 2 * Hn + c);
  } else {
    ir = *(const float4*)(bih + c);
    iz = *(const float4*)(bih + Hn + c);
    inn = *(const float4*)(bih + 2 * Hn + c);
  }
  float4 s;
  if (ST == 0) s = *(const float4*)((const float*)state_c + (size_t)m * Hn + c);
  else s = bf4(*(const uint2*)((const bfu*)state_c + (size_t)m * Hn + c));
  float4 o;
  {
    float r, z, n;
    r = sigf(ir.x + hr.x); z = sigf(iz.x + hz.x); n = tanhf(inn.x + r * hn.x);
    o.x = (1.f - z) * n + z * s.x;
    r = sigf(ir.y + hr.y); z = sigf(iz.y + hz.y); n = tanhf(inn.y + r * hn.y);
    o.y = (1.f - z) * n + z * s.y;
    r = sigf(ir.z + hr.z); z = sigf(iz.z + hz.z); n = tanhf(inn.z + r * hn.z);
    o.z = (1.f - z) * n + z * s.z;
    r = sigf(ir.w + hr.w); z = sigf(iz.w + hz.w); n = tanhf(inn.w + r * hn.w);
    o.w = (1.f - z) * n + z * s.w;
  }
  if (ST == 0) *(float4*)((float*)state_c + (size_t)m * Hn + c) = o;
  else *(uint2*)((bfu*)state_c + (size_t)m * Hn + c) = f2b4(o);
}

template <int ST>
__global__ void hdiff_k(const void* __restrict__ state, int off, float* __restrict__ Dh) {
  const int m = blockIdx.x, t = threadIdx.x;  // 128 threads x float4
  float4 a, b;
  if (ST == 0) {
    const float* st = (const float*)state;
    a = ((const float4*)(st + (size_t)(off + m) * Hn))[t];
    b = ((const float4*)(st + (size_t)(2 * Bn + off + m) * Hn))[t];
  } else {
    const bfu* st = (const bfu*)state;
    a = bf4(((const uint2*)(st + (size_t)(off + m) * Hn))[t]);
    b = bf4(((const uint2*)(st + (size_t)(2 * Bn + off + m) * Hn))[t]);
  }
  ((float4*)(Dh + (size_t)m * Hn))[t] =
      make_float4(a.x - b.x, a.y - b.y, a.z - b.z, a.w - b.w);
}

__global__ void relu_f_k(float* __restrict__ p, long n4) {
  long i = (long)blockIdx.x * blockDim.x + threadIdx.x;
  if (i < n4) {
    float4 v = ((float4*)p)[i];
    v.x = fmaxf(v.x, 0.f); v.y = fmaxf(v.y, 0.f);
    v.z = fmaxf(v.z, 0.f); v.w = fmaxf(v.w, 0.f);
    ((float4*)p)[i] = v;
  }
}

__global__ void relu_b_k(unsigned* __restrict__ p, long n) {
  long i = (long)blockIdx.x * blockDim.x + threadIdx.x;
  if (i < n) {
    unsigned v = p[i];
    p[i] = ((v & 0x8000u) ? 0u : (v & 0xFFFFu)) |
           ((v & 0x80000000u) ? 0u : (v & 0xFFFF0000u));
  }
}

// out[RC,32] = Hh[RC,512] @ W2[512,32] + b2; store per flag dtype.
__global__ void head2_k(const float* __restrict__ Hh, const float* __restrict__ W2,
                        const float* __restrict__ b2, void* __restrict__ out,
                        int rowOff, const int* __restrict__ flagp) {
  __shared__ __align__(16) float Ws[64][32];
  __shared__ __align__(16) float As2[8][64];
  const int t = threadIdx.x;
  const int r0 = blockIdx.x * 8;
  const int lr = t >> 5, c = t & 31;
  float acc = 0.f;
  for (int kc = 0; kc < 512; kc += 64) {
    __syncthreads();
    {
      const float4* src = (const float4*)(W2 + (size_t)kc * 32);
      float4* dst = (float4*)(&Ws[0][0]);
      dst[t] = src[t];
      dst[t + 256] = src[t + 256];
    }
    {
      const int i = t * 2;
      const int rr = i >> 6, cc = i & 63;
      float2 v = *(const float2*)(Hh + (size_t)(r0 + rr) * 512 + kc + cc);
      *(float2*)(&As2[rr][cc]) = v;
    }
    __syncthreads();
#pragma unroll
    for (int k = 0; k < 64; ++k) acc = fmaf(As2[lr][k], Ws[k][c], acc);
  }
  const float r = acc + b2[c];
  const size_t o = (size_t)(rowOff + r0 + lr) * 32 + c;
  if (flagp[0]) ((bfu*)out)[o] = (bfu)f2bu(r);
  else ((float*)out)[o] = r;
}

template <int ST>
static void run_all(void* const* d_in, void* d_out, void* d_ws, hipStream_t stream) {
  const int* a_ids = (const int*)d_in[0];
  const int* event_ids = (const int*)d_in[1];
  const int* b_ids = (const int*)d_in[2];
  const int* c_ids = (const int*)d_in[3];
  const void* text_ab = d_in[4];
  const void* ent_emb = d_in[5];

  char* w = (char*)d_ws;
  int* flag = (int*)w;      w += 256;
  float* wf = (float*)w;    w += (size_t)WF_TOTAL * 4;
  float* arena = (float*)w; w += (size_t)RC * 4096 * 4;
  char* state = w;
  const size_t esz = ST ? 2 : 4;

  float* hid = arena;                         // RC x 512
  float* Pc = arena + (size_t)RC * 512;       // RC x 512
  float* gi = arena + (size_t)RC * 1024;      // RC x 1536
  float* gh = arena + (size_t)RC * 2560;      // RC x 1536
  auto stRow = [&](size_t r) -> char* { return state + r * Hn * esz; };
  const dim3 blk(256);

  detect_k<<<dim3(1), blk, 0, stream>>>((const unsigned*)ent_emb, flag);

  struct CV { int idx; size_t off; int n; };
  const CV cvs[20] = {
      {6, OFF_TEXTW, 196608}, {7, OFF_TEXTB, 256},   {8, OFF_PROJW, 131072},
      {9, OFF_PROJB, 512},    {10, OFF_MSGW1, 532480}, {11, OFF_MSGB1, 1024},
      {12, OFF_MSGW2, 524288}, {13, OFF_MSGB2, 1024}, {14, OFF_ATTW1, 266240},
      {15, OFF_ATTB1, 512},   {16, OFF_ATTW2, 262144}, {17, OFF_ATTB2, 1024},
      {18, OFF_GWIH, 1572864}, {19, OFF_GWHH, 1572864}, {20, OFF_GBIH, 3072},
      {21, OFF_GBHH, 3072},   {22, OFF_HW1, 262144},  {23, OFF_HB1, 512},
      {24, OFF_HW2, 16384},   {25, OFF_HB2, 32}};
  for (int i = 0; i < 20; ++i)
    convert_k<<<dim3((cvs[i].n + 255) / 256), blk, 0, stream>>>(
        d_in[cvs[i].idx], wf + cvs[i].off, cvs[i].n, flag);

  for (int ii = 0; ii < 2; ++ii) {
    build_btype_k<<<dim3(6), blk, 0, stream>>>(
        wf + OFF_MSGB1 + ii * 512, wf + OFF_MSGW1 + (size_t)ii * 520 * 512 + 512 * 512,
        wf + OFF_BTM + ii * 1536, 512);
    build_btype_k<<<dim3(3), blk, 0, stream>>>(
        wf + OFF_ATTB1 + ii * 256, wf + OFF_ATTW1 + (size_t)ii * 520 * 256 + 512 * 256,
        wf + OFF_BTA + ii * 768, 256);
  }

  // ---- input phase: state = relu(proj(X)) in RC-row chunks ----
  const int* gids[3] = {a_ids, b_ids, c_ids};
  const size_t gdst[3] = {0, (size_t)2 * Bn, (size_t)3 * Bn};
  for (int g = 0; g < 3; ++g)
    for (int off = 0; off < Bn; off += RC) {
      gather_k<<<dim3(RC), dim3(64), 0, stream>>>(gids[g] + off, ent_emb, hid, flag);
      sgemm_k<EPI_RELU, 0, 0, ST><<<dim3(4, RC / 128), blk, 0, stream>>>(
          hid, wf + OFF_PROJW, wf + OFF_PROJB, nullptr, nullptr, nullptr,
          stRow(gdst[g] + off), RC, Hn, Dn, 0, flag);
    }
  for (int off = 0; off < Bn; off += RC) {
    sgemm_k<EPI_RELU_GATHER, 0, 1, 0><<<dim3(2, RC / 128), blk, 0, stream>>>(
        text_ab, wf + OFF_TEXTW, wf + OFF_TEXTB, nullptr, event_ids, ent_emb,
        hid, RC, Dn, Tn, off, flag);
    sgemm_k<EPI_RELU, 0, 0, ST><<<dim3(4, RC / 128), blk, 0, stream>>>(
        hid, wf + OFF_PROJW, wf + OFF_PROJB, nullptr, nullptr, nullptr,
        stRow((size_t)Bn + off), RC, Hn, Dn, 0, flag);
  }

  // ---- propagation ----
  for (int ii = 0; ii < 2; ++ii) {
    if (ii > 0) {
      if (ST == 0)
        relu_f_k<<<dim3(32768), blk, 0, stream>>>((float*)state, (long)4 * Bn * Hn / 4);
      else
        relu_b_k<<<dim3(65536), blk, 0, stream>>>((unsigned*)state, (long)4 * Bn * Hn / 2);
    }
    for (int p = 0; p < 2; ++p) {
      // descending node-chunk order: C(3), B(2), Event(1) have incoming edges
      // from chunk r-1 (updated later) and own rows (read pre-update). A(0) last.
      for (int r = 3; r >= 1; --r)
        for (int s = 0; s < Bn; s += RC) {
          const int e0 = (r - 1) * Bn + s;  // edge-id offset; type = r-1
          sgemm_k<EPI_RELU, 0, (ST ? 3 : 2), 0><<<dim3(4, RC / 128), blk, 0, stream>>>(
              state, wf + OFF_MSGW1 + (size_t)ii * 520 * 512,
              wf + OFF_BTM + ii * 1536 + (r - 1) * 512,
              nullptr, nullptr, nullptr, hid, RC, Hn, Hn, e0, flag);
          sgemm_k<EPI_NONE, 0, 0, 0><<<dim3(4, RC / 128), blk, 0, stream>>>(
              hid, wf + OFF_MSGW2 + (size_t)ii * 512 * 512, wf + OFF_MSGB2 + ii * 512,
              nullptr, nullptr, nullptr, Pc, RC, Hn, Hn, 0, flag);
          sgemm_k<EPI_RELU, 0, (ST ? 3 : 2), 0><<<dim3(2, RC / 128), blk, 0, stream>>>(
              state, wf + OFF_ATTW1 + (size_t)ii * 520 * 256,
              wf + OFF_BTA + ii * 768 + (r - 1) * 256,
              nullptr, nullptr, nullptr, hid, RC, 256, Hn, e0, flag);
          sgemm_k<EPI_SIG_MUL, 0, 0, 0><<<dim3(4, RC / 128), blk, 0, stream>>>(
              hid, wf + OFF_ATTW2 + (size_t)ii * 256 * 512, wf + OFF_ATTB2 + ii * 512,
              Pc, nullptr, nullptr, Pc, RC, Hn, 256, 0, flag);
          sgemm_k<EPI_NONE, 1, 0, 0><<<dim3(12, RC / 128), blk, 0, stream>>>(
              Pc, wf + OFF_GWIH + (size_t)ii * 1536 * 512, wf + OFF_GBIH + ii * 1536,
              nullptr, nullptr, nullptr, gi, RC, 3 * Hn, Hn, 0, flag);
          sgemm_k<EPI_NONE, 1, (ST ? 4 : 0), 0><<<dim3(12, RC / 128), blk, 0, stream>>>(
              stRow((size_t)r * Bn + s), wf + OFF_GWHH + (size_t)ii * 1536 * 512,
              wf + OFF_GBHH + ii * 1536, nullptr, nullptr, nullptr, gh, RC, 3 * Hn, Hn,
              0, flag);
          gru_gate_k<ST><<<dim3(RC / 2), blk, 0, stream>>>(
              gi, wf + OFF_GBIH + ii * 1536, gh, stRow((size_t)r * Bn + s));
        }
      for (int s = 0; s < Bn; s += RC) {  // r = 0: A nodes, agg == 0
        sgemm_k<EPI_NONE, 1, (ST ? 4 : 0), 0><<<dim3(12, RC / 128), blk, 0, stream>>>(
            stRow(s), wf + OFF_GWHH + (size_t)ii * 1536 * 512, wf + OFF_GBHH + ii * 1536,
            nullptr, nullptr, nullptr, gh, RC, 3 * Hn, Hn, 0, flag);
        gru_gate_k<ST><<<dim3(RC / 2), blk, 0, stream>>>(
            nullptr, wf + OFF_GBIH + ii * 1536, gh, stRow(s));
      }
    }
  }

  // ---- head, chunked through arena ----
  for (int off = 0; off < Bn; off += RC) {
    hdiff_k<ST><<<dim3(RC), dim3(128), 0, stream>>>(state, off, hid);
    sgemm_k<EPI_RELU, 0, 0, 0><<<dim3(4, RC / 128), blk, 0, stream>>>(
        hid, wf + OFF_HW1, wf + OFF_HB1, nullptr, nullptr, nullptr, Pc, RC, Hn, Hn,
        0, flag);
    head2_k<<<dim3(RC / 8), blk, 0, stream>>>(Pc, wf + OFF_HW2, wf + OFF_HB2, d_out,
                                              off, flag);
  }
}

extern "C" void kernel_launch(void* const* d_in, const int* in_sizes, int n_in,
                              void* d_out, int out_size, void* d_ws, size_t ws_size,
                              hipStream_t stream) {
  const size_t needBig = 256 + (size_t)WF_TOTAL * 4 + (size_t)RC * 4096 * 4 +
                         (size_t)4 * Bn * Hn * 4;  // 189,183,360 B
  if (ws_size >= needBig)
    run_all<0>(d_in, d_out, d_ws, stream);
  else
    run_all<1>(d_in, d_out, d_ws, stream);
}

// Round 5
// 16979.521 us; speedup vs baseline: 2.5448x; 2.5448x over previous
//
#include <hip/hip_runtime.h>
#include <math.h>

// GRANCascadingPredictor — round 5: full-width launches, fp16 intermediates.
//
// Facts established: ws_size >= 189,183,360 (big path passed R4); inputs are
// flag-dtyped (device probe), compute fp32, state fp32 (bit-faithful).
// R4 failure mode: 700 launches x 64-192-block grids = 25 TF realized.
//
// This round: edge MLPs run full-Bn (512-block grids); GRU split as
// g_rz (summed gi+gh, 2 accumulating passes), i_n, h_n in 4096-row chunks
// with a 64x128 tile (512/256-block grids). Transients (hid, P, gate
// preacts) stored fp16: each adds <=5e-4 rel; threshold has 6x headroom.
//
// ws: [flag 256B][weights fp32 21.36MB][arena 32MB: P 16 + scratch 16]
//     [state fp32 128MB]  = 189,129,984 <= proven ws_size.

#define Bn 16384
#define Hn 512
#define Dn 256
#define Tn 768
#define RCG 4096

#define EPI_NONE 0
#define EPI_RELU 1
#define EPI_SIG_MUL 2
#define EPI_RELU_GATHER 3
#define EPI_ADD 4

typedef unsigned short bfu;
typedef _Float16 f16;
typedef f16 h4 __attribute__((ext_vector_type(4)));

// weight-arena offsets (floats)
#define OFF_TEXTW 0
#define OFF_TEXTB 196608
#define OFF_PROJW 196864
#define OFF_PROJB 327936
#define OFF_MSGW1 328448
#define OFF_MSGB1 860928
#define OFF_MSGW2 861952
#define OFF_MSGB2 1386240
#define OFF_ATTW1 1387264
#define OFF_ATTB1 1653504
#define OFF_ATTW2 1654016
#define OFF_ATTB2 1916160
#define OFF_GWIH 1917184
#define OFF_GWHH 3490048
#define OFF_GBIH 5062912
#define OFF_GBHH 5065984
#define OFF_HW1 5069056
#define OFF_HB1 5331200
#define OFF_BTM 5331712
#define OFF_BTA 5334784
#define OFF_GRZ 5336320
#define OFF_ZERO 5338368
#define WF_TOTAL 5339392

__device__ __forceinline__ float sigf(float x) { return 1.f / (1.f + expf(-x)); }

__device__ __forceinline__ float b2f(bfu v) {
  union { unsigned q; float f; } c;
  c.q = (unsigned)v << 16;
  return c.f;
}

__device__ __forceinline__ float4 bf4(uint2 u) {
  union { unsigned q; float f; } c;
  float4 r;
  c.q = u.x << 16;          r.x = c.f;
  c.q = u.x & 0xFFFF0000u;  r.y = c.f;
  c.q = u.y << 16;          r.z = c.f;
  c.q = u.y & 0xFFFF0000u;  r.w = c.f;
  return r;
}

__device__ __forceinline__ unsigned f2bu(float x) {
  union { float f; unsigned u; } c;
  c.f = x;
  return (c.u + 0x7FFFu + ((c.u >> 16) & 1u)) >> 16;
}

__device__ __forceinline__ float4 h2f4(h4 h) {
  return make_float4((float)h.x, (float)h.y, (float)h.z, (float)h.w);
}
__device__ __forceinline__ h4 f2h4(float4 v) {
  h4 r;
  r.x = (f16)v.x; r.y = (f16)v.y; r.z = (f16)v.z; r.w = (f16)v.w;
  return r;
}

// flag=1 -> float tensors are bf16; flag=0 -> fp32.
__global__ void detect_k(const unsigned* __restrict__ p, int* __restrict__ flag) {
  __shared__ float red[256];
  const int t = threadIdx.x;
  union { unsigned q; float f; } c;
  c.q = p[t] << 16;
  float m = fabsf(c.f);
  if (!(m == m)) m = 1e30f;
  red[t] = m;
  __syncthreads();
  for (int s = 128; s > 0; s >>= 1) {
    if (t < s) red[t] = fmaxf(red[t], red[t + s]);
    __syncthreads();
  }
  if (t == 0) flag[0] = (red[0] < 1e3f) ? 1 : 0;
}

__global__ void convert_k(const void* __restrict__ src, float* __restrict__ dst,
                          int n, const int* __restrict__ flagp) {
  const int i = blockIdx.x * blockDim.x + threadIdx.x;
  if (i >= n) return;
  dst[i] = flagp[0] ? b2f(((const bfu*)src)[i]) : ((const float*)src)[i];
}

__global__ void build_btype_k(const float* __restrict__ b, const float* __restrict__ wr,
                              float* __restrict__ out, int N) {
  const int i = blockIdx.x * blockDim.x + threadIdx.x;
  if (i < 3 * N) out[i] = b[i % N] + wr[i];
}

__global__ void add_k(const float* __restrict__ a, const float* __restrict__ b,
                      float* __restrict__ o, int n) {
  const int i = blockIdx.x * blockDim.x + threadIdx.x;
  if (i < n) o[i] = a[i] + b[i];
}

// Xc[r] = ent_emb[ids[r]] -> fp32
__global__ void gather_k(const int* __restrict__ ids, const void* __restrict__ emb,
                         float* __restrict__ Xc, const int* __restrict__ flagp) {
  const int r = blockIdx.x, t = threadIdx.x;
  const int id = ids[r];
  float4 v;
  if (flagp[0])
    v = bf4(((const uint2*)((const bfu*)emb + (size_t)id * Dn))[t]);
  else
    v = ((const float4*)((const float*)emb + (size_t)id * Dn))[t];
  ((float4*)(Xc + (size_t)r * Dn))[t] = v;
}

// C[M,N] = epi(A @ W + bias). Tiles: TM x 128, 256 threads, fp32 accumulate.
// BT=0: W[K,N] fp32; BT=1: W[N,K] fp32 (B^T). bias fp32.
// AM: 0=A fp32 [M,K]; 1=A flag-dtyped global rows rowOff+row; 2=A row
//     e=rowOff+row -> state[src(e)]-state[e+Bn] (fp32); 5=A fp16 [M,K].
// CT: 0=C fp32; 2=C fp16.
// EPI_SIG_MUL: C=sigmoid(acc+bias)*extra (fp16, may alias C elementwise).
// EPI_ADD:     C=acc+bias+extra (fp16, may alias C elementwise).
// EPI_RELU_GATHER: C=relu(acc+bias)+gtab[gidx[row]] (flag dtype).
template <int EPI, int BT, int AM, int CT, int TM>
__global__ __launch_bounds__(256, 2) void sgemm_k(
    const void* __restrict__ Ap, const float* __restrict__ W,
    const float* __restrict__ bias, const void* __restrict__ extra,
    const int* __restrict__ gidx, const void* __restrict__ gtab,
    void* __restrict__ C, int M, int N, int K, int rowOff,
    const int* __restrict__ flagp) {
  __shared__ __align__(16) float As[8][TM];
  __shared__ __align__(16) float Bs[8][128];
  const int t = threadIdx.x;
  const int row0 = blockIdx.y * TM;
  const int col0 = blockIdx.x * 128;
  const int tx = t & 15, ty = t >> 4;
  const int arow = t >> 1;
  const int akof = (t & 1) * 4;
  const bool aAct = (TM == 128) || (t < 128);
  const int wk = t >> 5, wn = (t & 31) * 4;
  const int wrow = t >> 1, wkof = (t & 1) * 4;  // BT=1 loader
  const int fl = (AM == 1 || EPI == EPI_RELU_GATHER) ? flagp[0] : 0;

  float acc[(TM == 128 ? 8 : 4)][8];
#pragma unroll
  for (int i = 0; i < (TM == 128 ? 8 : 4); ++i)
#pragma unroll
    for (int j = 0; j < 8; ++j) acc[i][j] = 0.f;

  auto loadA = [&](int k) -> float4 {
    if (!aAct) return make_float4(0.f, 0.f, 0.f, 0.f);
    if (AM == 0) {
      return *(const float4*)((const float*)Ap + (size_t)(row0 + arow) * K + k + akof);
    } else if (AM == 1) {
      const size_t off = (size_t)(rowOff + row0 + arow) * K + k + akof;
      if (fl) return bf4(*(const uint2*)((const bfu*)Ap + off));
      return *(const float4*)((const float*)Ap + off);
    } else if (AM == 5) {
      return h2f4(*(const h4*)((const f16*)Ap + (size_t)(row0 + arow) * K + k + akof));
    } else {  // AM == 2
      const int e = rowOff + row0 + arow;
      const int s = (e < 2 * Bn) ? e : e - Bn;
      const float* st = (const float*)Ap;
      float4 x = *(const float4*)(st + (size_t)s * Hn + k + akof);
      float4 y = *(const float4*)(st + (size_t)(e + Bn) * Hn + k + akof);
      return make_float4(x.x - y.x, x.y - y.y, x.z - y.z, x.w - y.w);
    }
  };
  auto loadW = [&](int k) -> float4 {
    if (BT == 0)
      return *(const float4*)(W + (size_t)(k + wk) * N + col0 + wn);
    else
      return *(const float4*)(W + (size_t)(col0 + wrow) * K + k + wkof);
  };

  float4 aReg = loadA(0);
  float4 wReg = loadW(0);

  int k0 = 0;
  while (true) {
    __syncthreads();
    if (aAct) {
      As[akof + 0][arow] = aReg.x;
      As[akof + 1][arow] = aReg.y;
      As[akof + 2][arow] = aReg.z;
      As[akof + 3][arow] = aReg.w;
    }
    if (BT == 0) {
      *(float4*)(&Bs[wk][wn]) = wReg;
    } else {
      Bs[wkof + 0][wrow] = wReg.x;
      Bs[wkof + 1][wrow] = wReg.y;
      Bs[wkof + 2][wrow] = wReg.z;
      Bs[wkof + 3][wrow] = wReg.w;
    }
    __syncthreads();
    const int knext = k0 + 8;
    if (knext < K) {
      aReg = loadA(knext);
      wReg = loadW(knext);
    }
#pragma unroll
    for (int k = 0; k < 8; ++k) {
      float4 a0 = *(const float4*)(&As[k][ty * (TM == 128 ? 8 : 4)]);
      float4 a1 = (TM == 128) ? *(const float4*)(&As[k][ty * 8 + 4]) : a0;
      float4 b0 = *(const float4*)(&Bs[k][tx * 4]);
      float4 b1 = *(const float4*)(&Bs[k][64 + tx * 4]);
      float av[8] = {a0.x, a0.y, a0.z, a0.w, a1.x, a1.y, a1.z, a1.w};
      float bv[8] = {b0.x, b0.y, b0.z, b0.w, b1.x, b1.y, b1.z, b1.w};
#pragma unroll
      for (int i = 0; i < (TM == 128 ? 8 : 4); ++i)
#pragma unroll
        for (int j = 0; j < 8; ++j) acc[i][j] = fmaf(av[i], bv[j], acc[i][j]);
    }
    if (knext >= K) break;
    k0 = knext;
  }

  const int c0 = col0 + tx * 4;
  const int c1 = col0 + 64 + tx * 4;
  float4 bb0 = *(const float4*)(bias + c0);
  float4 bb1 = *(const float4*)(bias + c1);

#pragma unroll
  for (int i = 0; i < (TM == 128 ? 8 : 4); ++i) {
    const int row = row0 + ty * (TM == 128 ? 8 : 4) + i;
    float4 v0, v1;
    v0.x = acc[i][0] + bb0.x; v0.y = acc[i][1] + bb0.y;
    v0.z = acc[i][2] + bb0.z; v0.w = acc[i][3] + bb0.w;
    v1.x = acc[i][4] + bb1.x; v1.y = acc[i][5] + bb1.y;
    v1.z = acc[i][6] + bb1.z; v1.w = acc[i][7] + bb1.w;
    if (EPI == EPI_RELU || EPI == EPI_RELU_GATHER) {
      v0.x = fmaxf(v0.x, 0.f); v0.y = fmaxf(v0.y, 0.f);
      v0.z = fmaxf(v0.z, 0.f); v0.w = fmaxf(v0.w, 0.f);
      v1.x = fmaxf(v1.x, 0.f); v1.y = fmaxf(v1.y, 0.f);
      v1.z = fmaxf(v1.z, 0.f); v1.w = fmaxf(v1.w, 0.f);
    }
    if (EPI == EPI_SIG_MUL || EPI == EPI_ADD) {
      const f16* ep = (const f16*)extra + (size_t)row * N;
      float4 e0 = h2f4(*(const h4*)(ep + c0));
      float4 e1 = h2f4(*(const h4*)(ep + c1));
      if (EPI == EPI_SIG_MUL) {
        v0.x = sigf(v0.x) * e0.x; v0.y = sigf(v0.y) * e0.y;
        v0.z = sigf(v0.z) * e0.z; v0.w = sigf(v0.w) * e0.w;
        v1.x = sigf(v1.x) * e1.x; v1.y = sigf(v1.y) * e1.y;
        v1.z = sigf(v1.z) * e1.z; v1.w = sigf(v1.w) * e1.w;
      } else {
        v0.x += e0.x; v0.y += e0.y; v0.z += e0.z; v0.w += e0.w;
        v1.x += e1.x; v1.y += e1.y; v1.z += e1.z; v1.w += e1.w;
      }
    }
    if (EPI == EPI_RELU_GATHER) {
      const int grow = gidx[rowOff + row];
      float4 g0, g1;
      if (fl) {
        const bfu* g = (const bfu*)gtab + (size_t)grow * N;
        g0 = bf4(*(const uint2*)(g + c0));
        g1 = bf4(*(const uint2*)(g + c1));
      } else {
        const float* g = (const float*)gtab + (size_t)grow * N;
        g0 = *(const float4*)(g + c0);
        g1 = *(const float4*)(g + c1);
      }
      v0.x += g0.x; v0.y += g0.y; v0.z += g0.z; v0.w += g0.w;
      v1.x += g1.x; v1.y += g1.y; v1.z += g1.z; v1.w += g1.w;
    }
    if (CT == 0) {
      float* cp = (float*)C + (size_t)row * N;
      *(float4*)(cp + c0) = v0;
      *(float4*)(cp + c1) = v1;
    } else {
      f16* cp = (f16*)C + (size_t)row * N;
      *(h4*)(cp + c0) = f2h4(v0);
      *(h4*)(cp + c1) = f2h4(v1);
    }
  }
}

// GRU gate: r,z from summed preact gsum[m,1024]; n from i_n (or bihn), h_n.
__global__ void gru_gate_k(const f16* __restrict__ gsum, const f16* __restrict__ i_n,
                           const f16* __restrict__ h_n, const float* __restrict__ bihn,
                           float* __restrict__ st) {
  const int idx = blockIdx.x * blockDim.x + threadIdx.x;
  const int m = idx >> 7;
  const int c = (idx & 127) << 2;
  float4 ra = h2f4(*(const h4*)(gsum + (size_t)m * 1024 + c));
  float4 za = h2f4(*(const h4*)(gsum + (size_t)m * 1024 + 512 + c));
  float4 ia = i_n ? h2f4(*(const h4*)(i_n + (size_t)m * 512 + c))
                  : *(const float4*)(bihn + c);
  float4 ha = h2f4(*(const h4*)(h_n + (size_t)m * 512 + c));
  float* sp = st + (size_t)m * 512 + c;
  float4 s = *(const float4*)sp;
  float4 o;
  {
    float r, z, n;
    r = sigf(ra.x); z = sigf(za.x); n = tanhf(ia.x + r * ha.x);
    o.x = (1.f - z) * n + z * s.x;
    r = sigf(ra.y); z = sigf(za.y); n = tanhf(ia.y + r * ha.y);
    o.y = (1.f - z) * n + z * s.y;
    r = sigf(ra.z); z = sigf(za.z); n = tanhf(ia.z + r * ha.z);
    o.z = (1.f - z) * n + z * s.z;
    r = sigf(ra.w); z = sigf(za.w); n = tanhf(ia.w + r * ha.w);
    o.w = (1.f - z) * n + z * s.w;
  }
  *(float4*)sp = o;
}

__global__ void hdiff_k(const float* __restrict__ st, f16* __restrict__ Dh) {
  const int m = blockIdx.x, t = threadIdx.x;  // 128 thr x float4
  float4 a = ((const float4*)(st + (size_t)m * Hn))[t];
  float4 b = ((const float4*)(st + (size_t)(2 * Bn + m) * Hn))[t];
  ((h4*)(Dh + (size_t)m * Hn))[t] =
      f2h4(make_float4(a.x - b.x, a.y - b.y, a.z - b.z, a.w - b.w));
}

__global__ void relu_f_k(float* __restrict__ p, long n4) {
  long i = (long)blockIdx.x * blockDim.x + threadIdx.x;
  if (i < n4) {
    float4 v = ((float4*)p)[i];
    v.x = fmaxf(v.x, 0.f); v.y = fmaxf(v.y, 0.f);
    v.z = fmaxf(v.z, 0.f); v.w = fmaxf(v.w, 0.f);
    ((float4*)p)[i] = v;
  }
}

// out[Bn,32] = Hh(fp16)[Bn,512] @ W2[512,32] + b2; W2/b2/out flag-dtyped.
__global__ void head2_k(const f16* __restrict__ Hh, const void* __restrict__ W2,
                        const void* __restrict__ b2, void* __restrict__ out,
                        const int* __restrict__ flagp) {
  __shared__ __align__(16) float Ws[64][32];
  __shared__ __align__(16) float As2[8][64];
  const int t = threadIdx.x;
  const int r0 = blockIdx.x * 8;
  const int lr = t >> 5, c = t & 31;
  const int fl = flagp[0];
  float acc = 0.f;
  for (int kc = 0; kc < 512; kc += 64) {
    __syncthreads();
    if (fl) {
      uint4 u = ((const uint4*)((const bfu*)W2 + (size_t)kc * 32))[t];
      uint2 lo; lo.x = u.x; lo.y = u.y;
      uint2 hi; hi.x = u.z; hi.y = u.w;
      ((float4*)&Ws[0][0])[t * 2] = bf4(lo);
      ((float4*)&Ws[0][0])[t * 2 + 1] = bf4(hi);
    } else {
      const float4* src = (const float4*)((const float*)W2 + (size_t)kc * 32);
      ((float4*)&Ws[0][0])[t * 2] = src[t * 2];
      ((float4*)&Ws[0][0])[t * 2 + 1] = src[t * 2 + 1];
    }
    {
      const int i = t * 2, rr = i >> 6, cc = i & 63;
      const f16* hp = Hh + (size_t)(r0 + rr) * 512 + kc + cc;
      As2[rr][cc] = (float)hp[0];
      As2[rr][cc + 1] = (float)hp[1];
    }
    __syncthreads();
#pragma unroll
    for (int k = 0; k < 64; ++k) acc = fmaf(As2[lr][k], Ws[k][c], acc);
  }
  const float bb = fl ? b2f(((const bfu*)b2)[c]) : ((const float*)b2)[c];
  const float r = acc + bb;
  const size_t o = (size_t)(r0 + lr) * 32 + c;
  if (fl) ((bfu*)out)[o] = (bfu)f2bu(r);
  else ((float*)out)[o] = r;
}

extern "C" void kernel_launch(void* const* d_in, const int* in_sizes, int n_in,
                              void* d_out, int out_size, void* d_ws, size_t ws_size,
                              hipStream_t stream) {
  const int* a_ids = (const int*)d_in[0];
  const int* event_ids = (const int*)d_in[1];
  const int* b_ids = (const int*)d_in[2];
  const int* c_ids = (const int*)d_in[3];
  const void* text_ab = d_in[4];
  const void* ent_emb = d_in[5];

  char* w = (char*)d_ws;
  int* flag = (int*)w;   w += 256;
  float* wf = (float*)w; w += (size_t)WF_TOTAL * 4;
  f16* arena = (f16*)w;  w += (size_t)32 * 1024 * 1024;
  float* state = (float*)w;  // 4Bn x 512 fp32 = 128 MB

  f16* P = arena;                          // Bn x 512 fp16 (16 MB)
  f16* S = arena + (size_t)Bn * 512;       // 16 MB scratch
  f16* hid = S;                            // Bn x 512
  f16* ahid = S;                           // Bn x 256
  float* Xc = (float*)S;                   // Bn x 256 fp32
  f16* gsum = S;                           // RCG x 1024
  f16* i_n = S + (size_t)RCG * 1024;       // RCG x 512
  f16* h_n = S + (size_t)RCG * 1536;       // RCG x 512
  const dim3 blk(256);

  detect_k<<<dim3(1), blk, 0, stream>>>((const unsigned*)ent_emb, flag);

  struct CV { int idx; int off; int n; };
  const CV cvs[18] = {
      {6, OFF_TEXTW, 196608}, {7, OFF_TEXTB, 256},    {8, OFF_PROJW, 131072},
      {9, OFF_PROJB, 512},    {10, OFF_MSGW1, 532480}, {11, OFF_MSGB1, 1024},
      {12, OFF_MSGW2, 524288}, {13, OFF_MSGB2, 1024},  {14, OFF_ATTW1, 266240},
      {15, OFF_ATTB1, 512},   {16, OFF_ATTW2, 262144}, {17, OFF_ATTB2, 1024},
      {18, OFF_GWIH, 1572864}, {19, OFF_GWHH, 1572864}, {20, OFF_GBIH, 3072},
      {21, OFF_GBHH, 3072},   {22, OFF_HW1, 262144},   {23, OFF_HB1, 512}};
  for (int i = 0; i < 18; ++i)
    convert_k<<<dim3((cvs[i].n + 255) / 256), blk, 0, stream>>>(
        d_in[cvs[i].idx], wf + cvs[i].off, cvs[i].n, flag);

  hipMemsetAsync(wf + OFF_ZERO, 0, 1024 * 4, stream);
  for (int ii = 0; ii < 2; ++ii) {
    build_btype_k<<<dim3(6), blk, 0, stream>>>(
        wf + OFF_MSGB1 + ii * 512, wf + OFF_MSGW1 + (size_t)ii * 520 * 512 + 512 * 512,
        wf + OFF_BTM + ii * 1536, 512);
    build_btype_k<<<dim3(3), blk, 0, stream>>>(
        wf + OFF_ATTB1 + ii * 256, wf + OFF_ATTW1 + (size_t)ii * 520 * 256 + 512 * 256,
        wf + OFF_BTA + ii * 768, 256);
    add_k<<<dim3(4), blk, 0, stream>>>(wf + OFF_GBIH + ii * 1536,
                                       wf + OFF_GBHH + ii * 1536,
                                       wf + OFF_GRZ + ii * 1024, 1024);
  }

  // ---- input phase: state = relu(proj(X)), full-Bn launches ----
  const int* gids[3] = {a_ids, b_ids, c_ids};
  const size_t gdst[3] = {0, (size_t)2 * Bn, (size_t)3 * Bn};
  for (int g = 0; g < 3; ++g) {
    gather_k<<<dim3(Bn), dim3(64), 0, stream>>>(gids[g], ent_emb, Xc, flag);
    sgemm_k<EPI_RELU, 0, 0, 0, 128><<<dim3(4, 128), blk, 0, stream>>>(
        Xc, wf + OFF_PROJW, wf + OFF_PROJB, nullptr, nullptr, nullptr,
        state + gdst[g] * 512, Bn, Hn, Dn, 0, flag);
  }
  sgemm_k<EPI_RELU_GATHER, 0, 1, 0, 128><<<dim3(2, 128), blk, 0, stream>>>(
      text_ab, wf + OFF_TEXTW, wf + OFF_TEXTB, nullptr, event_ids, ent_emb,
      Xc, Bn, Dn, Tn, 0, flag);
  sgemm_k<EPI_RELU, 0, 0, 0, 128><<<dim3(4, 128), blk, 0, stream>>>(
      Xc, wf + OFF_PROJW, wf + OFF_PROJB, nullptr, nullptr, nullptr,
      state + (size_t)Bn * 512, Bn, Hn, Dn, 0, flag);

  // ---- propagation: stages r=3,2,1 (C,B,Event) then r=0 (A) ----
  for (int ii = 0; ii < 2; ++ii) {
    if (ii > 0)
      relu_f_k<<<dim3(32768), blk, 0, stream>>>(state, (long)4 * Bn * Hn / 4);
    const float* Wih = wf + OFF_GWIH + (size_t)ii * 1536 * 512;
    const float* Whh = wf + OFF_GWHH + (size_t)ii * 1536 * 512;
    for (int p = 0; p < 2; ++p) {
      for (int r = 3; r >= 1; --r) {
        const int e0 = (r - 1) * Bn;
        // P = sigmoid(att) * msg for all Bn edges of this type (fp16)
        sgemm_k<EPI_RELU, 0, 2, 2, 128><<<dim3(4, 128), blk, 0, stream>>>(
            state, wf + OFF_MSGW1 + (size_t)ii * 520 * 512,
            wf + OFF_BTM + ii * 1536 + (r - 1) * 512, nullptr, nullptr, nullptr,
            hid, Bn, Hn, Hn, e0, flag);
        sgemm_k<EPI_NONE, 0, 5, 2, 128><<<dim3(4, 128), blk, 0, stream>>>(
            hid, wf + OFF_MSGW2 + (size_t)ii * 512 * 512, wf + OFF_MSGB2 + ii * 512,
            nullptr, nullptr, nullptr, P, Bn, Hn, Hn, 0, flag);
        sgemm_k<EPI_RELU, 0, 2, 2, 128><<<dim3(2, 128), blk, 0, stream>>>(
            state, wf + OFF_ATTW1 + (size_t)ii * 520 * 256,
            wf + OFF_BTA + ii * 768 + (r - 1) * 256, nullptr, nullptr, nullptr,
            ahid, Bn, 256, Hn, e0, flag);
        sgemm_k<EPI_SIG_MUL, 0, 5, 2, 128><<<dim3(4, 128), blk, 0, stream>>>(
            ahid, wf + OFF_ATTW2 + (size_t)ii * 256 * 512, wf + OFF_ATTB2 + ii * 512,
            P, nullptr, nullptr, P, Bn, Hn, 256, 0, flag);
        // GRU for nodes r*Bn.. in RCG chunks
        for (int cdx = 0; cdx < Bn / RCG; ++cdx) {
          const f16* Pr = P + (size_t)cdx * RCG * 512;
          float* str = state + ((size_t)r * Bn + cdx * RCG) * 512;
          sgemm_k<EPI_NONE, 1, 5, 2, 64><<<dim3(8, RCG / 64), blk, 0, stream>>>(
              Pr, Wih, wf + OFF_GRZ + ii * 1024, nullptr, nullptr, nullptr,
              gsum, RCG, 1024, Hn, 0, flag);
          sgemm_k<EPI_ADD, 1, 0, 2, 64><<<dim3(8, RCG / 64), blk, 0, stream>>>(
              str, Whh, wf + OFF_ZERO, gsum, nullptr, nullptr,
              gsum, RCG, 1024, Hn, 0, flag);
          sgemm_k<EPI_NONE, 1, 5, 2, 64><<<dim3(4, RCG / 64), blk, 0, stream>>>(
              Pr, Wih + (size_t)1024 * 512, wf + OFF_GBIH + ii * 1536 + 1024,
              nullptr, nullptr, nullptr, i_n, RCG, 512, Hn, 0, flag);
          sgemm_k<EPI_NONE, 1, 0, 2, 64><<<dim3(4, RCG / 64), blk, 0, stream>>>(
              str, Whh + (size_t)1024 * 512, wf + OFF_GBHH + ii * 1536 + 1024,
              nullptr, nullptr, nullptr, h_n, RCG, 512, Hn, 0, flag);
          gru_gate_k<<<dim3(RCG * 128 / 256), blk, 0, stream>>>(
              gsum, i_n, h_n, nullptr, str);
        }
      }
      // r = 0 (A nodes): agg == 0 -> gi = bih
      for (int cdx = 0; cdx < Bn / RCG; ++cdx) {
        float* str = state + ((size_t)cdx * RCG) * 512;
        sgemm_k<EPI_NONE, 1, 0, 2, 64><<<dim3(8, RCG / 64), blk, 0, stream>>>(
            str, Whh, wf + OFF_GRZ + ii * 1024, nullptr, nullptr, nullptr,
            gsum, RCG, 1024, Hn, 0, flag);
        sgemm_k<EPI_NONE, 1, 0, 2, 64><<<dim3(4, RCG / 64), blk, 0, stream>>>(
            str, Whh + (size_t)1024 * 512, wf + OFF_GBHH + ii * 1536 + 1024,
            nullptr, nullptr, nullptr, h_n, RCG, 512, Hn, 0, flag);
        gru_gate_k<<<dim3(RCG * 128 / 256), blk, 0, stream>>>(
            gsum, nullptr, h_n, wf + OFF_GBIH + ii * 1536 + 1024, str);
      }
    }
  }

  // ---- head ----
  hdiff_k<<<dim3(Bn), dim3(128), 0, stream>>>(state, S);
  sgemm_k<EPI_RELU, 0, 5, 2, 128><<<dim3(4, 128), blk, 0, stream>>>(
      S, wf + OFF_HW1, wf + OFF_HB1, nullptr, nullptr, nullptr, P, Bn, Hn, Hn,
      0, flag);
  head2_k<<<dim3(Bn / 8), blk, 0, stream>>>(P, d_in[24], d_in[25], d_out, flag);
}

// Round 6
// 5501.542 us; speedup vs baseline: 7.8540x; 3.0863x over previous
//
#include <hip/hip_runtime.h>
#include <math.h>

// GRANCascadingPredictor — round 6: fp16 MFMA (v_mfma_f32_16x16x32_f16).
//
// Established: ws_size >= 189,183,360; inputs flag-dtyped (device probe);
// state fp32 (128 MB); fp16 intermediates cost ~2e-6 absmax (R5).
// R5 = 17 ms, VALU-bound at 43% of fp32 peak -> move matmuls to matrix pipe.
//
// GEMM: 128x128 tile, 4 waves 2x2, each wave 4x4 of 16x16x32 MFMAs, K-step
// 32, LDS row-major +8-half pad (80 B stride, 16B aligned, 2-way bank alias
// = free), register-prefetch pipeline. Fragment layouts (m89/m120-verified):
//   A: [m=lane&15][k=quad*8+j]   B: [k=quad*8+j][n=lane&15]
//   C/D: [row=quad*4+reg][col=lane&15]
// All weights pre-converted once/call to fp16 Wt[N][K] (GRU W already [N,K]).
//
// ws map (186,835,200 B < 189,183,360 proven):
//   flag 256 | fp32 biases 56 KB | fp16 Wt 10.6 MB | P 16 MB | S 24 MB
//   | state fp32 128 MB

#define Bn 16384
#define Hn 512
#define Dn 256
#define Tn 768
#define RCG 4096

#define EPI_NONE 0
#define EPI_RELU 1
#define EPI_SIG_MUL 2
#define EPI_RELU_GATHER 3

typedef unsigned short bfu;
typedef _Float16 f16;
typedef f16 h4 __attribute__((ext_vector_type(4)));
typedef f16 half8 __attribute__((ext_vector_type(8)));
typedef float floatx4 __attribute__((ext_vector_type(4)));

// fp16 weight arena offsets (halves)
#define HTEXTW 0
#define HPROJW 196608
#define HMSGW1 327680
#define HMSGW2 851968
#define HATTW1 1376256
#define HATTW2 1638400
#define HGWIH 1900544
#define HGWHH 3473408
#define HHW1 5046272
#define HTOTAL 5308416
// fp32 bias arena offsets (floats)
#define FTEXTB 0
#define FPROJB 256
#define FMSGB2 768
#define FATTB2 1792
#define FGBIH 2816
#define FGBHH 5888
#define FHB1 8960
#define FBTM 9472
#define FBTA 12544

__device__ __forceinline__ float sigf(float x) { return 1.f / (1.f + expf(-x)); }

__device__ __forceinline__ float b2f(bfu v) {
  union { unsigned q; float f; } c;
  c.q = (unsigned)v << 16;
  return c.f;
}

__device__ __forceinline__ float4 bf4(uint2 u) {
  union { unsigned q; float f; } c;
  float4 r;
  c.q = u.x << 16;          r.x = c.f;
  c.q = u.x & 0xFFFF0000u;  r.y = c.f;
  c.q = u.y << 16;          r.z = c.f;
  c.q = u.y & 0xFFFF0000u;  r.w = c.f;
  return r;
}

__device__ __forceinline__ unsigned f2bu(float x) {
  union { float f; unsigned u; } c;
  c.f = x;
  return (c.u + 0x7FFFu + ((c.u >> 16) & 1u)) >> 16;
}

__device__ __forceinline__ float4 h2f4(h4 h) {
  return make_float4((float)h.x, (float)h.y, (float)h.z, (float)h.w);
}
__device__ __forceinline__ h4 f2h4c(float4 v) {
  h4 r;
  r.x = (f16)v.x; r.y = (f16)v.y; r.z = (f16)v.z; r.w = (f16)v.w;
  return r;
}
__device__ __forceinline__ half8 ff2h8(float4 a, float4 b) {
  half8 r;
  r[0] = (f16)a.x; r[1] = (f16)a.y; r[2] = (f16)a.z; r[3] = (f16)a.w;
  r[4] = (f16)b.x; r[5] = (f16)b.y; r[6] = (f16)b.z; r[7] = (f16)b.w;
  return r;
}
__device__ __forceinline__ half8 bf2h8(uint4 u) {
  uint2 lo; lo.x = u.x; lo.y = u.y;
  uint2 hi; hi.x = u.z; hi.y = u.w;
  return ff2h8(bf4(lo), bf4(hi));
}

// flag=1 -> float tensors are bf16; flag=0 -> fp32.
__global__ void detect_k(const unsigned* __restrict__ p, int* __restrict__ flag) {
  __shared__ float red[256];
  const int t = threadIdx.x;
  union { unsigned q; float f; } c;
  c.q = p[t] << 16;
  float m = fabsf(c.f);
  if (!(m == m)) m = 1e30f;
  red[t] = m;
  __syncthreads();
  for (int s = 128; s > 0; s >>= 1) {
    if (t < s) red[t] = fmaxf(red[t], red[t + s]);
    __syncthreads();
  }
  if (t == 0) flag[0] = (red[0] < 1e3f) ? 1 : 0;
}

__device__ __forceinline__ float cvld(const void* p, size_t i, int fl) {
  return fl ? b2f(((const bfu*)p)[i]) : ((const float*)p)[i];
}

// fp32 bias convert (with element offset; flag-dtyped src)
__global__ void convF_k(const void* __restrict__ src, size_t off, float* __restrict__ dst,
                        int n, const int* __restrict__ flagp) {
  const int i = blockIdx.x * 256 + threadIdx.x;
  if (i < n) dst[i] = cvld(src, off + i, flagp[0]);
}

// plain fp16 convert (for GRU weights already in [N,K] layout)
__global__ void convH_k(const void* __restrict__ src, size_t off, f16* __restrict__ dst,
                        int n, const int* __restrict__ flagp) {
  const int i = blockIdx.x * 256 + threadIdx.x;
  if (i < n) dst[i] = (f16)cvld(src, off + i, flagp[0]);
}

// transpose-convert: src[K,N] (flag dtype) -> dst[N][K] fp16, 32x32 tiles
__global__ void convT_k(const void* __restrict__ src, size_t off, f16* __restrict__ dst,
                        int K, int N, const int* __restrict__ flagp) {
  __shared__ f16 tile[32][33];
  const int t = threadIdx.x;
  const int c = t & 31, r0 = t >> 5;
  const int kb = blockIdx.y * 32, nb = blockIdx.x * 32;
  const int fl = flagp[0];
#pragma unroll
  for (int i = 0; i < 4; ++i) {
    const int k = kb + r0 + i * 8, n = nb + c;
    tile[r0 + i * 8][c] = (f16)cvld(src, off + (size_t)k * N + n, fl);
  }
  __syncthreads();
#pragma unroll
  for (int i = 0; i < 4; ++i) {
    const int n = nb + r0 + i * 8, k = kb + c;
    dst[(size_t)n * K + k] = tile[c][r0 + i * 8];
  }
}

// per-edge-type folded bias: dst[i] = b[i%N] + wr[i], i < 3N (fp32)
__global__ void btype_k(const void* __restrict__ b, size_t bOff,
                        const void* __restrict__ wr, size_t wrOff,
                        float* __restrict__ dst, int N, const int* __restrict__ flagp) {
  const int i = blockIdx.x * 256 + threadIdx.x;
  const int fl = flagp[0];
  if (i < 3 * N) dst[i] = cvld(b, bOff + i % N, fl) + cvld(wr, wrOff + i, fl);
}

// Xc[r] = ent_emb[ids[r]] -> fp16
__global__ void gather_k(const int* __restrict__ ids, const void* __restrict__ emb,
                         f16* __restrict__ Xc, const int* __restrict__ flagp) {
  const int r = blockIdx.x, t = threadIdx.x;
  const int id = ids[r];
  float4 v;
  if (flagp[0])
    v = bf4(((const uint2*)((const bfu*)emb + (size_t)id * Dn))[t]);
  else
    v = ((const float4*)((const float*)emb + (size_t)id * Dn))[t];
  ((h4*)(Xc + (size_t)r * Dn))[t] = f2h4c(v);
}

// C[M,N] = epi(A[M,K] @ W + bias) with MFMA. W = Wt[N][K] fp16. bias fp32.
// AM: 0=A fp32 [M,K]; 1=A flag-dtyped global rows rowOff+row; 2=A row
//     e=rowOff+row -> state[src(e)]-state[e+Bn] (fp32, K==Hn); 5=A fp16.
// CT: 0=C fp32; 2=C fp16.
// EPI_SIG_MUL: C=sigmoid(acc+bias)*extra (fp16, may alias C elementwise).
// EPI_RELU_GATHER: C=relu(acc+bias)+gtab[gidx[rowOff+row]*N+col] (flag dtype).
template <int EPI, int AM, int CT>
__global__ __launch_bounds__(256, 2) void hgemm_k(
    const void* __restrict__ Ap, const f16* __restrict__ Wt,
    const float* __restrict__ bias, const void* __restrict__ extra,
    const int* __restrict__ gidx, const void* __restrict__ gtab,
    void* __restrict__ C, int M, int N, int K, int rowOff,
    const int* __restrict__ flagp) {
  __shared__ __align__(16) f16 As[128][40];  // +8 pad: 80 B stride, 16B aligned
  __shared__ __align__(16) f16 Bs[128][40];  // Bs[n][k]
  const int t = threadIdx.x;
  const int row0 = blockIdx.y * 128;
  const int col0 = blockIdx.x * 128;
  const int lane = t & 63;
  const int wv = t >> 6;
  const int wm = wv >> 1, wn = wv & 1;
  const int l16 = lane & 15, quad = lane >> 4;
  const int arow = t & 127;          // staging row (A) / n-row (B)
  const int ak0 = (t >> 7) * 8;      // staging k-offset: {0,8}, +16 for seg 1
  const int fl = (AM == 1 || EPI == EPI_RELU_GATHER) ? flagp[0] : 0;

  floatx4 acc[4][4];
#pragma unroll
  for (int mi = 0; mi < 4; ++mi)
#pragma unroll
    for (int ni = 0; ni < 4; ++ni) acc[mi][ni] = (floatx4){0.f, 0.f, 0.f, 0.f};

  auto fetchA = [&](int kk, int seg) -> half8 {
    const int k = kk + ak0 + seg * 16;
    if (AM == 5) {
      return *(const half8*)((const f16*)Ap + (size_t)(row0 + arow) * K + k);
    } else if (AM == 0) {
      const float* ap = (const float*)Ap + (size_t)(row0 + arow) * K + k;
      return ff2h8(*(const float4*)ap, *(const float4*)(ap + 4));
    } else if (AM == 1) {
      const size_t o = (size_t)(rowOff + row0 + arow) * K + k;
      if (fl) return bf2h8(*(const uint4*)((const bfu*)Ap + o));
      const float* ap = (const float*)Ap + o;
      return ff2h8(*(const float4*)ap, *(const float4*)(ap + 4));
    } else {  // AM == 2: state-diff rows
      const int e = rowOff + row0 + arow;
      const int s = (e < 2 * Bn) ? e : e - Bn;
      const float* st = (const float*)Ap;
      const float* xp = st + (size_t)s * Hn + k;
      const float* yp = st + (size_t)(e + Bn) * Hn + k;
      float4 x0 = *(const float4*)xp, x1 = *(const float4*)(xp + 4);
      float4 y0 = *(const float4*)yp, y1 = *(const float4*)(yp + 4);
      float4 d0 = make_float4(x0.x - y0.x, x0.y - y0.y, x0.z - y0.z, x0.w - y0.w);
      float4 d1 = make_float4(x1.x - y1.x, x1.y - y1.y, x1.z - y1.z, x1.w - y1.w);
      return ff2h8(d0, d1);
    }
  };
  auto fetchB = [&](int kk, int seg) -> half8 {
    return *(const half8*)(Wt + (size_t)(col0 + arow) * K + kk + ak0 + seg * 16);
  };

  half8 pa0 = fetchA(0, 0), pa1 = fetchA(0, 1);
  half8 pb0 = fetchB(0, 0), pb1 = fetchB(0, 1);

  int kt = 0;
  while (true) {
    __syncthreads();
    *(half8*)&As[arow][ak0] = pa0;
    *(half8*)&As[arow][ak0 + 16] = pa1;
    *(half8*)&Bs[arow][ak0] = pb0;
    *(half8*)&Bs[arow][ak0 + 16] = pb1;
    __syncthreads();
    const int kn = kt + 32;
    if (kn < K) {
      pa0 = fetchA(kn, 0); pa1 = fetchA(kn, 1);
      pb0 = fetchB(kn, 0); pb1 = fetchB(kn, 1);
    }
    half8 a8[4], b8[4];
#pragma unroll
    for (int mi = 0; mi < 4; ++mi)
      a8[mi] = *(const half8*)&As[wm * 64 + mi * 16 + l16][quad * 8];
#pragma unroll
    for (int ni = 0; ni < 4; ++ni)
      b8[ni] = *(const half8*)&Bs[wn * 64 + ni * 16 + l16][quad * 8];
#pragma unroll
    for (int mi = 0; mi < 4; ++mi)
#pragma unroll
      for (int ni = 0; ni < 4; ++ni)
        acc[mi][ni] = __builtin_amdgcn_mfma_f32_16x16x32_f16(a8[mi], b8[ni],
                                                             acc[mi][ni], 0, 0, 0);
    if (kn >= K) break;
    kt = kn;
  }

  // epilogue: C/D layout row = quad*4+reg, col = lane&15 per 16x16 tile
  const int colBase = col0 + wn * 64;
  const int rowBase = row0 + wm * 64;
#pragma unroll
  for (int mi = 0; mi < 4; ++mi) {
    const int r0r = rowBase + mi * 16 + quad * 4;
#pragma unroll
    for (int ni = 0; ni < 4; ++ni) {
      const int col = colBase + ni * 16 + l16;
      const float bb = bias[col];
      floatx4 v = acc[mi][ni];
#pragma unroll
      for (int rg = 0; rg < 4; ++rg) {
        const int row = r0r + rg;
        float x = v[rg] + bb;
        if (EPI == EPI_RELU || EPI == EPI_RELU_GATHER) x = fmaxf(x, 0.f);
        if (EPI == EPI_SIG_MUL) {
          const float e = (float)((const f16*)extra)[(size_t)row * N + col];
          x = sigf(x) * e;
        }
        if (EPI == EPI_RELU_GATHER) {
          const int grow = gidx[rowOff + row];
          x += fl ? b2f(((const bfu*)gtab)[(size_t)grow * N + col])
                  : ((const float*)gtab)[(size_t)grow * N + col];
        }
        if (CT == 0)
          ((float*)C)[(size_t)row * N + col] = x;
        else
          ((f16*)C)[(size_t)row * N + col] = (f16)x;
      }
    }
  }
}

// GRU gate: gi/gh fp16 [M,1536] = [r z n] preacts incl. biases; gi==nullptr ->
// A-node chunk (agg==0): i-preacts = bih (fp32). state fp32 updated in place.
__global__ void gru_gate_k(const f16* __restrict__ gi, const float* __restrict__ bih,
                           const f16* __restrict__ gh, float* __restrict__ st) {
  const int idx = blockIdx.x * blockDim.x + threadIdx.x;
  const int m = idx >> 7;
  const int c = (idx & 127) << 2;
  const f16* gp = gh + (size_t)m * 1536;
  float4 hr = h2f4(*(const h4*)(gp + c));
  float4 hz = h2f4(*(const h4*)(gp + 512 + c));
  float4 hn = h2f4(*(const h4*)(gp + 1024 + c));
  float4 ir, iz, inx;
  if (gi) {
    const f16* ip = gi + (size_t)m * 1536;
    ir = h2f4(*(const h4*)(ip + c));
    iz = h2f4(*(const h4*)(ip + 512 + c));
    inx = h2f4(*(const h4*)(ip + 1024 + c));
  } else {
    ir = *(const float4*)(bih + c);
    iz = *(const float4*)(bih + 512 + c);
    inx = *(const float4*)(bih + 1024 + c);
  }
  float* sp = st + (size_t)m * 512 + c;
  float4 s = *(const float4*)sp;
  float4 o;
  {
    float r, z, n;
    r = sigf(ir.x + hr.x); z = sigf(iz.x + hz.x); n = tanhf(inx.x + r * hn.x);
    o.x = (1.f - z) * n + z * s.x;
    r = sigf(ir.y + hr.y); z = sigf(iz.y + hz.y); n = tanhf(inx.y + r * hn.y);
    o.y = (1.f - z) * n + z * s.y;
    r = sigf(ir.z + hr.z); z = sigf(iz.z + hz.z); n = tanhf(inx.z + r * hn.z);
    o.z = (1.f - z) * n + z * s.z;
    r = sigf(ir.w + hr.w); z = sigf(iz.w + hz.w); n = tanhf(inx.w + r * hn.w);
    o.w = (1.f - z) * n + z * s.w;
  }
  *(float4*)sp = o;
}

__global__ void hdiff_k(const float* __restrict__ st, f16* __restrict__ Dh) {
  const int m = blockIdx.x, t = threadIdx.x;  // 128 thr x 4
  float4 a = ((const float4*)(st + (size_t)m * Hn))[t];
  float4 b = ((const float4*)(st + (size_t)(2 * Bn + m) * Hn))[t];
  ((h4*)(Dh + (size_t)m * Hn))[t] =
      f2h4c(make_float4(a.x - b.x, a.y - b.y, a.z - b.z, a.w - b.w));
}

__global__ void relu_f_k(float* __restrict__ p, long n4) {
  long i = (long)blockIdx.x * blockDim.x + threadIdx.x;
  if (i < n4) {
    float4 v = ((float4*)p)[i];
    v.x = fmaxf(v.x, 0.f); v.y = fmaxf(v.y, 0.f);
    v.z = fmaxf(v.z, 0.f); v.w = fmaxf(v.w, 0.f);
    ((float4*)p)[i] = v;
  }
}

// out[Bn,32] = Hh(fp16)[Bn,512] @ W2[512,32] + b2; W2/b2/out flag-dtyped.
__global__ void head2_k(const f16* __restrict__ Hh, const void* __restrict__ W2,
                        const void* __restrict__ b2, void* __restrict__ out,
                        const int* __restrict__ flagp) {
  __shared__ __align__(16) float Ws[64][32];
  __shared__ __align__(16) float As2[8][64];
  const int t = threadIdx.x;
  const int r0 = blockIdx.x * 8;
  const int lr = t >> 5, c = t & 31;
  const int fl = flagp[0];
  float acc = 0.f;
  for (int kc = 0; kc < 512; kc += 64) {
    __syncthreads();
    if (fl) {
      uint4 u = ((const uint4*)((const bfu*)W2 + (size_t)kc * 32))[t];
      uint2 lo; lo.x = u.x; lo.y = u.y;
      uint2 hi; hi.x = u.z; hi.y = u.w;
      ((float4*)&Ws[0][0])[t * 2] = bf4(lo);
      ((float4*)&Ws[0][0])[t * 2 + 1] = bf4(hi);
    } else {
      const float4* src = (const float4*)((const float*)W2 + (size_t)kc * 32);
      ((float4*)&Ws[0][0])[t * 2] = src[t * 2];
      ((float4*)&Ws[0][0])[t * 2 + 1] = src[t * 2 + 1];
    }
    {
      const int i = t * 2, rr = i >> 6, cc = i & 63;
      const f16* hp = Hh + (size_t)(r0 + rr) * 512 + kc + cc;
      As2[rr][cc] = (float)hp[0];
      As2[rr][cc + 1] = (float)hp[1];
    }
    __syncthreads();
#pragma unroll
    for (int k = 0; k < 64; ++k) acc = fmaf(As2[lr][k], Ws[k][c], acc);
  }
  const float bb = fl ? b2f(((const bfu*)b2)[c]) : ((const float*)b2)[c];
  const float r = acc + bb;
  const size_t o = (size_t)(r0 + lr) * 32 + c;
  if (fl) ((bfu*)out)[o] = (bfu)f2bu(r);
  else ((float*)out)[o] = r;
}

extern "C" void kernel_launch(void* const* d_in, const int* in_sizes, int n_in,
                              void* d_out, int out_size, void* d_ws, size_t ws_size,
                              hipStream_t stream) {
  const int* a_ids = (const int*)d_in[0];
  const int* event_ids = (const int*)d_in[1];
  const int* b_ids = (const int*)d_in[2];
  const int* c_ids = (const int*)d_in[3];
  const void* text_ab = d_in[4];
  const void* ent_emb = d_in[5];

  char* w = (char*)d_ws;
  int* flag = (int*)w;   w += 256;
  float* bf = (float*)w; w += 57344;              // fp32 biases (14336 floats)
  f16* hw = (f16*)w;     w += (size_t)HTOTAL * 2; // fp16 Wt arena, 10.6 MB
  f16* P = (f16*)w;      w += (size_t)Bn * 512 * 2;  // 16 MB
  f16* S = (f16*)w;      w += 25165824;           // 24 MB scratch
  float* state = (float*)w;                       // 128 MB
  f16* Xc = S;
  f16* hid = S;
  f16* ahid = S;
  const dim3 blk(256);

  detect_k<<<dim3(1), blk, 0, stream>>>((const unsigned*)ent_emb, flag);

  // ---- fp32 biases ----
  struct CF { int idx; size_t off; int dst; int n; };
  const CF cfs[7] = {{7, 0, FTEXTB, 256},  {9, 0, FPROJB, 512},
                     {13, 0, FMSGB2, 1024}, {17, 0, FATTB2, 1024},
                     {20, 0, FGBIH, 3072},  {21, 0, FGBHH, 3072},
                     {23, 0, FHB1, 512}};
  for (int i = 0; i < 7; ++i)
    convF_k<<<dim3((cfs[i].n + 255) / 256), blk, 0, stream>>>(
        d_in[cfs[i].idx], cfs[i].off, bf + cfs[i].dst, cfs[i].n, flag);

  // ---- fp16 weights: transpose-convert [K,N]->[N][K] ----
  convT_k<<<dim3(8, 24), blk, 0, stream>>>(d_in[6], 0, hw + HTEXTW, Tn, Dn, flag);
  convT_k<<<dim3(16, 8), blk, 0, stream>>>(d_in[8], 0, hw + HPROJW, Dn, Hn, flag);
  convT_k<<<dim3(16, 16), blk, 0, stream>>>(d_in[22], 0, hw + HHW1, Hn, Hn, flag);
  for (int ii = 0; ii < 2; ++ii) {
    convT_k<<<dim3(16, 16), blk, 0, stream>>>(
        d_in[10], (size_t)ii * 520 * 512, hw + HMSGW1 + ii * 262144, Hn, Hn, flag);
    convT_k<<<dim3(16, 16), blk, 0, stream>>>(
        d_in[12], (size_t)ii * 512 * 512, hw + HMSGW2 + ii * 262144, Hn, Hn, flag);
    convT_k<<<dim3(8, 16), blk, 0, stream>>>(
        d_in[14], (size_t)ii * 520 * 256, hw + HATTW1 + ii * 131072, Hn, 256, flag);
    convT_k<<<dim3(16, 8), blk, 0, stream>>>(
        d_in[16], (size_t)ii * 256 * 512, hw + HATTW2 + ii * 131072, 256, Hn, flag);
    convH_k<<<dim3(3072), blk, 0, stream>>>(
        d_in[18], (size_t)ii * 786432, hw + HGWIH + ii * 786432, 786432, flag);
    convH_k<<<dim3(3072), blk, 0, stream>>>(
        d_in[19], (size_t)ii * 786432, hw + HGWHH + ii * 786432, 786432, flag);
    btype_k<<<dim3(6), blk, 0, stream>>>(
        d_in[11], (size_t)ii * 512, d_in[10], (size_t)ii * 520 * 512 + 512 * 512,
        bf + FBTM + ii * 1536, 512, flag);
    btype_k<<<dim3(3), blk, 0, stream>>>(
        d_in[15], (size_t)ii * 256, d_in[14], (size_t)ii * 520 * 256 + 512 * 256,
        bf + FBTA + ii * 768, 256, flag);
  }

  // ---- input phase: state = relu(proj(X)) ----
  const int* gids[3] = {a_ids, b_ids, c_ids};
  const size_t gdst[3] = {0, (size_t)2 * Bn, (size_t)3 * Bn};
  for (int g = 0; g < 3; ++g) {
    gather_k<<<dim3(Bn), dim3(64), 0, stream>>>(gids[g], ent_emb, Xc, flag);
    hgemm_k<EPI_RELU, 5, 0><<<dim3(4, 128), blk, 0, stream>>>(
        Xc, hw + HPROJW, bf + FPROJB, nullptr, nullptr, nullptr,
        state + gdst[g] * 512, Bn, Hn, Dn, 0, flag);
  }
  hgemm_k<EPI_RELU_GATHER, 1, 2><<<dim3(2, 128), blk, 0, stream>>>(
      text_ab, hw + HTEXTW, bf + FTEXTB, nullptr, event_ids, ent_emb,
      Xc, Bn, Dn, Tn, 0, flag);
  hgemm_k<EPI_RELU, 5, 0><<<dim3(4, 128), blk, 0, stream>>>(
      Xc, hw + HPROJW, bf + FPROJB, nullptr, nullptr, nullptr,
      state + (size_t)Bn * 512, Bn, Hn, Dn, 0, flag);

  // ---- propagation: stages r=3,2,1 (C,B,Event) then r=0 (A) ----
  f16* gi = S;                          // RCG x 1536 (12 MB)
  f16* gh = S + (size_t)RCG * 1536;     // RCG x 1536 (12 MB)
  for (int ii = 0; ii < 2; ++ii) {
    if (ii > 0)
      relu_f_k<<<dim3(32768), blk, 0, stream>>>(state, (long)4 * Bn * Hn / 4);
    const f16* Wih = hw + HGWIH + (size_t)ii * 786432;
    const f16* Whh = hw + HGWHH + (size_t)ii * 786432;
    for (int p = 0; p < 2; ++p) {
      for (int r = 3; r >= 1; --r) {
        const int e0 = (r - 1) * Bn;
        hgemm_k<EPI_RELU, 2, 2><<<dim3(4, 128), blk, 0, stream>>>(
            state, hw + HMSGW1 + ii * 262144, bf + FBTM + ii * 1536 + (r - 1) * 512,
            nullptr, nullptr, nullptr, hid, Bn, Hn, Hn, e0, flag);
        hgemm_k<EPI_NONE, 5, 2><<<dim3(4, 128), blk, 0, stream>>>(
            hid, hw + HMSGW2 + ii * 262144, bf + FMSGB2 + ii * 512,
            nullptr, nullptr, nullptr, P, Bn, Hn, Hn, 0, flag);
        hgemm_k<EPI_RELU, 2, 2><<<dim3(2, 128), blk, 0, stream>>>(
            state, hw + HATTW1 + ii * 131072, bf + FBTA + ii * 768 + (r - 1) * 256,
            nullptr, nullptr, nullptr, ahid, Bn, 256, Hn, e0, flag);
        hgemm_k<EPI_SIG_MUL, 5, 2><<<dim3(4, 128), blk, 0, stream>>>(
            ahid, hw + HATTW2 + ii * 131072, bf + FATTB2 + ii * 512,
            P, nullptr, nullptr, P, Bn, Hn, 256, 0, flag);
        for (int cdx = 0; cdx < Bn / RCG; ++cdx) {
          float* str = state + ((size_t)r * Bn + cdx * RCG) * 512;
          hgemm_k<EPI_NONE, 5, 2><<<dim3(12, 32), blk, 0, stream>>>(
              P + (size_t)cdx * RCG * 512, Wih, bf + FGBIH + ii * 1536,
              nullptr, nullptr, nullptr, gi, RCG, 1536, Hn, 0, flag);
          hgemm_k<EPI_NONE, 0, 2><<<dim3(12, 32), blk, 0, stream>>>(
              str, Whh, bf + FGBHH + ii * 1536,
              nullptr, nullptr, nullptr, gh, RCG, 1536, Hn, 0, flag);
          gru_gate_k<<<dim3(RCG / 2), blk, 0, stream>>>(
              gi, bf + FGBIH + ii * 1536, gh, str);
        }
      }
      for (int cdx = 0; cdx < Bn / RCG; ++cdx) {  // r=0: A nodes, agg==0
        float* str = state + ((size_t)cdx * RCG) * 512;
        hgemm_k<EPI_NONE, 0, 2><<<dim3(12, 32), blk, 0, stream>>>(
            str, Whh, bf + FGBHH + ii * 1536,
            nullptr, nullptr, nullptr, gh, RCG, 1536, Hn, 0, flag);
        gru_gate_k<<<dim3(RCG / 2), blk, 0, stream>>>(
            nullptr, bf + FGBIH + ii * 1536, gh, str);
      }
    }
  }

  // ---- head ----
  hdiff_k<<<dim3(Bn), dim3(128), 0, stream>>>(state, S);
  hgemm_k<EPI_RELU, 5, 2><<<dim3(4, 128), blk, 0, stream>>>(
      S, hw + HHW1, bf + FHB1, nullptr, nullptr, nullptr, P, Bn, Hn, Hn, 0, flag);
  head2_k<<<dim3(Bn / 8), blk, 0, stream>>>(P, d_in[24], d_in[25], d_out, flag);
}

// Round 7
// 5052.662 us; speedup vs baseline: 8.5518x; 1.0888x over previous
//
#include <hip/hip_runtime.h>
#include <math.h>

// GRANCascadingPredictor — round 7: epilogue-fused GRU + merged edge MLPs.
//
// Established: ws >= 189,183,360; flag-dtyped inputs (device probe); state
// fp32 (bit-faithful path, absmax 1.9e-6 at R6); fp16 MFMA 16x16x32, verified
// frag layouts: A[m=lane&15][k=quad*8+j], B[k][n=lane&15], C/D[row=quad*4+reg]
// [col=lane&15].
//
// R6 -> R7 changes (theory: GRU = 77% of FLOPs, was 224 small launches +
// a separate gate pass re-reading 600MB/(ii,p)):
//  * GRU: RZ = sigmoid([P|state] @ [Wih_rz|Whh_rz]^T + bihrz+bhhrz)  (K=1024)
//         HN = state @ Whh_n^T + bhh_n
//         G3: i_n GEMM, epilogue n=tanh(i_n + r*h_n); state=(1-z)n+z*state
//    -> no gate kernel, no gi/gh buffers, 2 chunks of 8192 rows.
//  * E1 merges msg1+att1: one N=768 GEMM over state-diff A (read once).
//  * B-loader virtualizes the [Wih_rz|Whh_rz] concat (2 ptrs, saves 4MB).
//
// ws: flag 256 | bias fp32 64KB | fp16 weights 10.6MB | P 16MB | SH 24MB
//     | state fp32 128MB = 186.8MB.

#define Bn 16384
#define Hn 512
#define Dn 256
#define Tn 768
#define RCG 8192

#define EPI_NONE 0
#define EPI_RELU 1
#define EPI_SIG 2
#define EPI_SIGMUL 3
#define EPI_RELUGATHER 4
#define EPI_GRU 5

typedef unsigned short bfu;
typedef _Float16 f16;
typedef f16 h4 __attribute__((ext_vector_type(4)));
typedef f16 half8 __attribute__((ext_vector_type(8)));
typedef float floatx4 __attribute__((ext_vector_type(4)));

// fp16 weight arena offsets (halves)
#define HTEXTW 0
#define HPROJW 196608
#define HHW1 327680
#define HWE1 589824
#define HMSGW2 1376256
#define HATTW2 1900544
#define HWIH 2162688
#define HWHH 3735552
#define HTOTAL 5308416
// fp32 bias arena offsets (floats)
#define FTEXTB 0
#define FPROJB 256
#define FHB1 768
#define FGBIH 1280
#define FGBHH 4352
#define FBGRZ 7424
#define FBE1 9472
#define FBE2 14080

__device__ __forceinline__ float sigf(float x) { return 1.f / (1.f + expf(-x)); }

__device__ __forceinline__ float b2f(bfu v) {
  union { unsigned q; float f; } c;
  c.q = (unsigned)v << 16;
  return c.f;
}
__device__ __forceinline__ float4 bf4(uint2 u) {
  union { unsigned q; float f; } c;
  float4 r;
  c.q = u.x << 16;          r.x = c.f;
  c.q = u.x & 0xFFFF0000u;  r.y = c.f;
  c.q = u.y << 16;          r.z = c.f;
  c.q = u.y & 0xFFFF0000u;  r.w = c.f;
  return r;
}
__device__ __forceinline__ unsigned f2bu(float x) {
  union { float f; unsigned u; } c;
  c.f = x;
  return (c.u + 0x7FFFu + ((c.u >> 16) & 1u)) >> 16;
}
__device__ __forceinline__ float4 h2f4(h4 h) {
  return make_float4((float)h.x, (float)h.y, (float)h.z, (float)h.w);
}
__device__ __forceinline__ h4 f2h4c(float4 v) {
  h4 r;
  r.x = (f16)v.x; r.y = (f16)v.y; r.z = (f16)v.z; r.w = (f16)v.w;
  return r;
}
__device__ __forceinline__ half8 ff2h8(float4 a, float4 b) {
  half8 r;
  r[0] = (f16)a.x; r[1] = (f16)a.y; r[2] = (f16)a.z; r[3] = (f16)a.w;
  r[4] = (f16)b.x; r[5] = (f16)b.y; r[6] = (f16)b.z; r[7] = (f16)b.w;
  return r;
}
__device__ __forceinline__ half8 bf2h8(uint4 u) {
  uint2 lo; lo.x = u.x; lo.y = u.y;
  uint2 hi; hi.x = u.z; hi.y = u.w;
  return ff2h8(bf4(lo), bf4(hi));
}

__global__ void detect_k(const unsigned* __restrict__ p, int* __restrict__ flag) {
  __shared__ float red[256];
  const int t = threadIdx.x;
  union { unsigned q; float f; } c;
  c.q = p[t] << 16;
  float m = fabsf(c.f);
  if (!(m == m)) m = 1e30f;
  red[t] = m;
  __syncthreads();
  for (int s = 128; s > 0; s >>= 1) {
    if (t < s) red[t] = fmaxf(red[t], red[t + s]);
    __syncthreads();
  }
  if (t == 0) flag[0] = (red[0] < 1e3f) ? 1 : 0;
}

__device__ __forceinline__ float cvld(const void* p, size_t i, int fl) {
  return fl ? b2f(((const bfu*)p)[i]) : ((const float*)p)[i];
}

__global__ void convF_k(const void* __restrict__ src, size_t off, float* __restrict__ dst,
                        int n, const int* __restrict__ flagp) {
  const int i = blockIdx.x * 256 + threadIdx.x;
  if (i < n) dst[i] = cvld(src, off + i, flagp[0]);
}
__global__ void convH_k(const void* __restrict__ src, size_t off, f16* __restrict__ dst,
                        int n, const int* __restrict__ flagp) {
  const int i = blockIdx.x * 256 + threadIdx.x;
  if (i < n) dst[i] = (f16)cvld(src, off + i, flagp[0]);
}
__global__ void convT_k(const void* __restrict__ src, size_t off, f16* __restrict__ dst,
                        int K, int N, const int* __restrict__ flagp) {
  __shared__ f16 tile[32][33];
  const int t = threadIdx.x;
  const int c = t & 31, r0 = t >> 5;
  const int kb = blockIdx.y * 32, nb = blockIdx.x * 32;
  const int fl = flagp[0];
#pragma unroll
  for (int i = 0; i < 4; ++i)
    tile[r0 + i * 8][c] = (f16)cvld(src, off + (size_t)(kb + r0 + i * 8) * N + nb + c, fl);
  __syncthreads();
#pragma unroll
  for (int i = 0; i < 4; ++i)
    dst[(size_t)(nb + r0 + i * 8) * K + kb + c] = tile[c][r0 + i * 8];
}
__global__ void addv_k(const float* __restrict__ a, const float* __restrict__ b,
                       float* __restrict__ o, int n) {
  const int i = blockIdx.x * 256 + threadIdx.x;
  if (i < n) o[i] = a[i] + b[i];
}
// dst[t*dstStride + n] = b[n] + wr[t*N + n], t<3
__global__ void btype_k(const void* __restrict__ b, size_t bOff,
                        const void* __restrict__ wr, size_t wrOff,
                        float* __restrict__ dst, int N, int dstStride,
                        const int* __restrict__ flagp) {
  const int i = blockIdx.x * 256 + threadIdx.x;
  const int fl = flagp[0];
  if (i < 3 * N) {
    const int t = i / N, n = i % N;
    dst[(size_t)t * dstStride + n] = cvld(b, bOff + n, fl) + cvld(wr, wrOff + i, fl);
  }
}
__global__ void gather_k(const int* __restrict__ ids, const void* __restrict__ emb,
                         f16* __restrict__ Xc, const int* __restrict__ flagp) {
  const int r = blockIdx.x, t = threadIdx.x;
  const int id = ids[r];
  float4 v;
  if (flagp[0])
    v = bf4(((const uint2*)((const bfu*)emb + (size_t)id * Dn))[t]);
  else
    v = ((const float4*)((const float*)emb + (size_t)id * Dn))[t];
  ((h4*)(Xc + (size_t)r * Dn))[t] = f2h4c(v);
}

// C[M,N] = epi(A @ W + bias), MFMA 16x16x32, 128x128 tile, 4 waves 2x2.
// AM: 0=A fp32 (stride aStride); 1=A flag-dtyped global rows rowOff+row;
//     2=A row e=rowOff+row -> state[src(e)]-state[e+Bn] (fp32, stride 512);
//     5=A fp16 (stride aStride); 6=A=[P fp16 | state fp32], k<512->Ap, else Ap2.
// BM: 0=Wt[N][K] fp16; 1=concat k<512->Wt[n][k], else Wt2[n][k-512] (stride 512).
// CT: 0=C fp32; 2=C fp16 (ignored for EPI_GRU which writes fp32 state).
// EPI_SIG: store sigmoid. EPI_SIGMUL: sigf(x)*ex1[row*N+col] (may alias C).
// EPI_RELUGATHER: relu(x)+gtab[gidx[rowOff+row]*N+col]. EPI_GRU: r,z from
// ex1[row*1024+{col,512+col}], hn=ex2[row*512+col], s=C (fp32, in-place).
template <int EPI, int AM, int BM, int CT>
__global__ __launch_bounds__(256, 2) void hgemm_k(
    const void* __restrict__ Ap, const void* __restrict__ Ap2,
    const f16* __restrict__ Wt, const f16* __restrict__ Wt2,
    const float* __restrict__ bias,
    const f16* __restrict__ ex1, const f16* __restrict__ ex2,
    const int* __restrict__ gidx, const void* __restrict__ gtab,
    void* __restrict__ C, int N, int K, int aStride, int rowOff,
    const int* __restrict__ flagp) {
  __shared__ __align__(16) f16 As[128][40];
  __shared__ __align__(16) f16 Bs[128][40];
  const int t = threadIdx.x;
  const int row0 = blockIdx.y * 128;
  const int col0 = blockIdx.x * 128;
  const int lane = t & 63;
  const int wv = t >> 6;
  const int wm = wv >> 1, wn = wv & 1;
  const int l16 = lane & 15, quad = lane >> 4;
  const int arow = t & 127;
  const int ak0 = (t >> 7) * 8;
  const int fl = (AM == 1 || EPI == EPI_RELUGATHER) ? flagp[0] : 0;

  floatx4 acc[4][4];
#pragma unroll
  for (int mi = 0; mi < 4; ++mi)
#pragma unroll
    for (int ni = 0; ni < 4; ++ni) acc[mi][ni] = (floatx4){0.f, 0.f, 0.f, 0.f};

  auto fetchA = [&](int kk, int seg) -> half8 {
    const int k = kk + ak0 + seg * 16;
    const int m = row0 + arow;
    if (AM == 5) {
      return *(const half8*)((const f16*)Ap + (size_t)m * aStride + k);
    } else if (AM == 0) {
      const float* ap = (const float*)Ap + (size_t)m * aStride + k;
      return ff2h8(*(const float4*)ap, *(const float4*)(ap + 4));
    } else if (AM == 1) {
      const size_t o = (size_t)(rowOff + m) * aStride + k;
      if (fl) return bf2h8(*(const uint4*)((const bfu*)Ap + o));
      const float* ap = (const float*)Ap + o;
      return ff2h8(*(const float4*)ap, *(const float4*)(ap + 4));
    } else if (AM == 6) {
      if (k < 512) return *(const half8*)((const f16*)Ap + (size_t)m * 512 + k);
      const float* ap = (const float*)Ap2 + (size_t)m * 512 + (k - 512);
      return ff2h8(*(const float4*)ap, *(const float4*)(ap + 4));
    } else {  // AM == 2: state-diff rows
      const int e = rowOff + m;
      const int s = (e < 2 * Bn) ? e : e - Bn;
      const float* st = (const float*)Ap;
      const float* xp = st + (size_t)s * 512 + k;
      const float* yp = st + (size_t)(e + Bn) * 512 + k;
      float4 x0 = *(const float4*)xp, x1 = *(const float4*)(xp + 4);
      float4 y0 = *(const float4*)yp, y1 = *(const float4*)(yp + 4);
      return ff2h8(
          make_float4(x0.x - y0.x, x0.y - y0.y, x0.z - y0.z, x0.w - y0.w),
          make_float4(x1.x - y1.x, x1.y - y1.y, x1.z - y1.z, x1.w - y1.w));
    }
  };
  auto fetchB = [&](int kk, int seg) -> half8 {
    const int k = kk + ak0 + seg * 16;
    const int n = col0 + arow;
    if (BM == 0) return *(const half8*)(Wt + (size_t)n * K + k);
    if (k < 512) return *(const half8*)(Wt + (size_t)n * 512 + k);
    return *(const half8*)(Wt2 + (size_t)n * 512 + k - 512);
  };

  half8 pa0 = fetchA(0, 0), pa1 = fetchA(0, 1);
  half8 pb0 = fetchB(0, 0), pb1 = fetchB(0, 1);

  int kt = 0;
  while (true) {
    __syncthreads();
    *(half8*)&As[arow][ak0] = pa0;
    *(half8*)&As[arow][ak0 + 16] = pa1;
    *(half8*)&Bs[arow][ak0] = pb0;
    *(half8*)&Bs[arow][ak0 + 16] = pb1;
    __syncthreads();
    const int kn = kt + 32;
    if (kn < K) {
      pa0 = fetchA(kn, 0); pa1 = fetchA(kn, 1);
      pb0 = fetchB(kn, 0); pb1 = fetchB(kn, 1);
    }
    half8 a8[4], b8[4];
#pragma unroll
    for (int mi = 0; mi < 4; ++mi)
      a8[mi] = *(const half8*)&As[wm * 64 + mi * 16 + l16][quad * 8];
#pragma unroll
    for (int ni = 0; ni < 4; ++ni)
      b8[ni] = *(const half8*)&Bs[wn * 64 + ni * 16 + l16][quad * 8];
#pragma unroll
    for (int mi = 0; mi < 4; ++mi)
#pragma unroll
      for (int ni = 0; ni < 4; ++ni)
        acc[mi][ni] = __builtin_amdgcn_mfma_f32_16x16x32_f16(a8[mi], b8[ni],
                                                             acc[mi][ni], 0, 0, 0);
    if (kn >= K) break;
    kt = kn;
  }

  const int colBase = col0 + wn * 64;
  const int rowBase = row0 + wm * 64;
#pragma unroll
  for (int mi = 0; mi < 4; ++mi) {
    const int r0r = rowBase + mi * 16 + quad * 4;
#pragma unroll
    for (int ni = 0; ni < 4; ++ni) {
      const int col = colBase + ni * 16 + l16;
      const float bb = bias[col];
      floatx4 v = acc[mi][ni];
#pragma unroll
      for (int rg = 0; rg < 4; ++rg) {
        const int row = r0r + rg;
        float x = v[rg] + bb;
        if (EPI == EPI_RELU || EPI == EPI_RELUGATHER) x = fmaxf(x, 0.f);
        if (EPI == EPI_SIG) x = sigf(x);
        if (EPI == EPI_SIGMUL)
          x = sigf(x) * (float)ex1[(size_t)row * N + col];
        if (EPI == EPI_RELUGATHER) {
          const int grow = gidx[rowOff + row];
          x += fl ? b2f(((const bfu*)gtab)[(size_t)grow * N + col])
                  : ((const float*)gtab)[(size_t)grow * N + col];
        }
        if (EPI == EPI_GRU) {
          const float r_ = (float)ex1[(size_t)row * 1024 + col];
          const float z_ = (float)ex1[(size_t)row * 1024 + 512 + col];
          const float hn = (float)ex2[(size_t)row * 512 + col];
          float* cf = (float*)C + (size_t)row * 512 + col;
          const float s = *cf;
          const float n_ = tanhf(x + r_ * hn);
          *cf = (1.f - z_) * n_ + z_ * s;
        } else if (CT == 0) {
          ((float*)C)[(size_t)row * N + col] = x;
        } else {
          ((f16*)C)[(size_t)row * N + col] = (f16)x;
        }
      }
    }
  }
}

// r=0 (A nodes, agg==0): i_n = bih_n; elementwise state update over one chunk.
__global__ void gate0_k(const f16* __restrict__ RZ, const f16* __restrict__ HN,
                        const float* __restrict__ bihn, float* __restrict__ st) {
  const int idx = blockIdx.x * blockDim.x + threadIdx.x;
  const int m = idx >> 7;
  const int c = (idx & 127) << 2;
  float4 r4 = h2f4(*(const h4*)(RZ + (size_t)m * 1024 + c));
  float4 z4 = h2f4(*(const h4*)(RZ + (size_t)m * 1024 + 512 + c));
  float4 hn = h2f4(*(const h4*)(HN + (size_t)m * 512 + c));
  float4 b4 = *(const float4*)(bihn + c);
  float* sp = st + (size_t)m * 512 + c;
  float4 s = *(const float4*)sp;
  float4 o;
  float n_;
  n_ = tanhf(b4.x + r4.x * hn.x); o.x = (1.f - z4.x) * n_ + z4.x * s.x;
  n_ = tanhf(b4.y + r4.y * hn.y); o.y = (1.f - z4.y) * n_ + z4.y * s.y;
  n_ = tanhf(b4.z + r4.z * hn.z); o.z = (1.f - z4.z) * n_ + z4.z * s.z;
  n_ = tanhf(b4.w + r4.w * hn.w); o.w = (1.f - z4.w) * n_ + z4.w * s.w;
  *(float4*)sp = o;
}

__global__ void hdiff_k(const float* __restrict__ st, f16* __restrict__ Dh) {
  const int m = blockIdx.x, t = threadIdx.x;
  float4 a = ((const float4*)(st + (size_t)m * Hn))[t];
  float4 b = ((const float4*)(st + (size_t)(2 * Bn + m) * Hn))[t];
  ((h4*)(Dh + (size_t)m * Hn))[t] =
      f2h4c(make_float4(a.x - b.x, a.y - b.y, a.z - b.z, a.w - b.w));
}

__global__ void relu_f_k(float* __restrict__ p, long n4) {
  long i = (long)blockIdx.x * blockDim.x + threadIdx.x;
  if (i < n4) {
    float4 v = ((float4*)p)[i];
    v.x = fmaxf(v.x, 0.f); v.y = fmaxf(v.y, 0.f);
    v.z = fmaxf(v.z, 0.f); v.w = fmaxf(v.w, 0.f);
    ((float4*)p)[i] = v;
  }
}

__global__ void head2_k(const f16* __restrict__ Hh, const void* __restrict__ W2,
                        const void* __restrict__ b2, void* __restrict__ out,
                        const int* __restrict__ flagp) {
  __shared__ __align__(16) float Ws[64][32];
  __shared__ __align__(16) float As2[8][64];
  const int t = threadIdx.x;
  const int r0 = blockIdx.x * 8;
  const int lr = t >> 5, c = t & 31;
  const int fl = flagp[0];
  float acc = 0.f;
  for (int kc = 0; kc < 512; kc += 64) {
    __syncthreads();
    if (fl) {
      uint4 u = ((const uint4*)((const bfu*)W2 + (size_t)kc * 32))[t];
      uint2 lo; lo.x = u.x; lo.y = u.y;
      uint2 hi; hi.x = u.z; hi.y = u.w;
      ((float4*)&Ws[0][0])[t * 2] = bf4(lo);
      ((float4*)&Ws[0][0])[t * 2 + 1] = bf4(hi);
    } else {
      const float4* src = (const float4*)((const float*)W2 + (size_t)kc * 32);
      ((float4*)&Ws[0][0])[t * 2] = src[t * 2];
      ((float4*)&Ws[0][0])[t * 2 + 1] = src[t * 2 + 1];
    }
    {
      const int i = t * 2, rr = i >> 6, cc = i & 63;
      const f16* hp = Hh + (size_t)(r0 + rr) * 512 + kc + cc;
      As2[rr][cc] = (float)hp[0];
      As2[rr][cc + 1] = (float)hp[1];
    }
    __syncthreads();
#pragma unroll
    for (int k = 0; k < 64; ++k) acc = fmaf(As2[lr][k], Ws[k][c], acc);
  }
  const float bb = fl ? b2f(((const bfu*)b2)[c]) : ((const float*)b2)[c];
  const float r = acc + bb;
  const size_t o = (size_t)(r0 + lr) * 32 + c;
  if (fl) ((bfu*)out)[o] = (bfu)f2bu(r);
  else ((float*)out)[o] = r;
}

extern "C" void kernel_launch(void* const* d_in, const int* in_sizes, int n_in,
                              void* d_out, int out_size, void* d_ws, size_t ws_size,
                              hipStream_t stream) {
  const int* a_ids = (const int*)d_in[0];
  const int* event_ids = (const int*)d_in[1];
  const int* b_ids = (const int*)d_in[2];
  const int* c_ids = (const int*)d_in[3];
  const void* text_ab = d_in[4];
  const void* ent_emb = d_in[5];

  char* w = (char*)d_ws;
  int* flag = (int*)w;   w += 256;
  float* bf = (float*)w; w += 65536;               // fp32 biases
  f16* hw = (f16*)w;     w += (size_t)HTOTAL * 2;  // 10.6 MB
  f16* P = (f16*)w;      w += (size_t)Bn * 512 * 2;    // 16 MB
  f16* SH = (f16*)w;     w += (size_t)Bn * 768 * 2;    // 24 MB (hid / RZ+HN)
  float* state = (float*)w;                        // 128 MB
  f16* RZ = SH;                        // RCG x 1024
  f16* HN = SH + (size_t)RCG * 1024;   // RCG x 512
  const dim3 blk(256);

  detect_k<<<dim3(1), blk, 0, stream>>>((const unsigned*)ent_emb, flag);

  // ---- fp32 biases ----
  struct CF { int idx; size_t off; int dst; int n; };
  const CF cfs[9] = {{7, 0, FTEXTB, 256},   {9, 0, FPROJB, 512},
                     {23, 0, FHB1, 512},    {20, 0, FGBIH, 3072},
                     {21, 0, FGBHH, 3072},  {13, 0, FBE2, 512},
                     {17, 0, FBE2 + 512, 512}, {13, 512, FBE2 + 1024, 512},
                     {17, 512, FBE2 + 1536, 512}};
  for (int i = 0; i < 9; ++i)
    convF_k<<<dim3((cfs[i].n + 255) / 256), blk, 0, stream>>>(
        d_in[cfs[i].idx], cfs[i].off, bf + cfs[i].dst, cfs[i].n, flag);

  // ---- fp16 weights ----
  convT_k<<<dim3(8, 24), blk, 0, stream>>>(d_in[6], 0, hw + HTEXTW, Tn, Dn, flag);
  convT_k<<<dim3(16, 8), blk, 0, stream>>>(d_in[8], 0, hw + HPROJW, Dn, Hn, flag);
  convT_k<<<dim3(16, 16), blk, 0, stream>>>(d_in[22], 0, hw + HHW1, Hn, Hn, flag);
  for (int ii = 0; ii < 2; ++ii) {
    convT_k<<<dim3(16, 16), blk, 0, stream>>>(
        d_in[10], (size_t)ii * 520 * 512, hw + HWE1 + ii * 393216, Hn, Hn, flag);
    convT_k<<<dim3(8, 16), blk, 0, stream>>>(
        d_in[14], (size_t)ii * 520 * 256, hw + HWE1 + ii * 393216 + 262144, Hn, 256, flag);
    convT_k<<<dim3(16, 16), blk, 0, stream>>>(
        d_in[12], (size_t)ii * 512 * 512, hw + HMSGW2 + ii * 262144, Hn, Hn, flag);
    convT_k<<<dim3(16, 8), blk, 0, stream>>>(
        d_in[16], (size_t)ii * 256 * 512, hw + HATTW2 + ii * 131072, 256, Hn, flag);
    convH_k<<<dim3(3072), blk, 0, stream>>>(
        d_in[18], (size_t)ii * 786432, hw + HWIH + ii * 786432, 786432, flag);
    convH_k<<<dim3(3072), blk, 0, stream>>>(
        d_in[19], (size_t)ii * 786432, hw + HWHH + ii * 786432, 786432, flag);
    addv_k<<<dim3(4), blk, 0, stream>>>(bf + FGBIH + ii * 1536, bf + FGBHH + ii * 1536,
                                        bf + FBGRZ + ii * 1024, 1024);
    btype_k<<<dim3(6), blk, 0, stream>>>(
        d_in[11], (size_t)ii * 512, d_in[10], (size_t)ii * 520 * 512 + 512 * 512,
        bf + FBE1 + ii * 2304, 512, 768, flag);
    btype_k<<<dim3(3), blk, 0, stream>>>(
        d_in[15], (size_t)ii * 256, d_in[14], (size_t)ii * 520 * 256 + 512 * 256,
        bf + FBE1 + ii * 2304 + 512, 256, 768, flag);
  }

  // ---- input phase ----
  f16* Xc = SH;
  const int* gids[3] = {a_ids, b_ids, c_ids};
  const size_t gdst[3] = {0, (size_t)2 * Bn, (size_t)3 * Bn};
  for (int g = 0; g < 3; ++g) {
    gather_k<<<dim3(Bn), dim3(64), 0, stream>>>(gids[g], ent_emb, Xc, flag);
    hgemm_k<EPI_RELU, 5, 0, 0><<<dim3(4, 128), blk, 0, stream>>>(
        Xc, nullptr, hw + HPROJW, nullptr, bf + FPROJB, nullptr, nullptr,
        nullptr, nullptr, state + gdst[g] * 512, Hn, Dn, Dn, 0, flag);
  }
  hgemm_k<EPI_RELUGATHER, 1, 0, 2><<<dim3(2, 128), blk, 0, stream>>>(
      text_ab, nullptr, hw + HTEXTW, nullptr, bf + FTEXTB, nullptr, nullptr,
      event_ids, ent_emb, Xc, Dn, Tn, Tn, 0, flag);
  hgemm_k<EPI_RELU, 5, 0, 0><<<dim3(4, 128), blk, 0, stream>>>(
      Xc, nullptr, hw + HPROJW, nullptr, bf + FPROJB, nullptr, nullptr,
      nullptr, nullptr, state + (size_t)Bn * 512, Hn, Dn, Dn, 0, flag);

  // ---- propagation ----
  for (int ii = 0; ii < 2; ++ii) {
    if (ii > 0)
      relu_f_k<<<dim3(32768), blk, 0, stream>>>(state, (long)4 * Bn * Hn / 4);
    const f16* Wih = hw + HWIH + (size_t)ii * 786432;
    const f16* Whh = hw + HWHH + (size_t)ii * 786432;
    const f16* Win = Wih + (size_t)1024 * 512;
    const f16* Whn = Whh + (size_t)1024 * 512;
    const float* bgrz = bf + FBGRZ + ii * 1024;
    const float* bihn = bf + FGBIH + ii * 1536 + 1024;
    const float* bhhn = bf + FGBHH + ii * 1536 + 1024;
    for (int p = 0; p < 2; ++p) {
      for (int r = 3; r >= 1; --r) {
        const int e0 = (r - 1) * Bn;
        // E1: hid[Bn,768] = relu(diff @ [msgW1|attW1] + btype)
        hgemm_k<EPI_RELU, 2, 0, 2><<<dim3(6, 128), blk, 0, stream>>>(
            state, nullptr, hw + HWE1 + ii * 393216, nullptr,
            bf + FBE1 + ii * 2304 + (r - 1) * 768, nullptr, nullptr,
            nullptr, nullptr, SH, 768, Hn, 512, e0, flag);
        // E2a: P = hid[:,0:512] @ msgW2 + b2
        hgemm_k<EPI_NONE, 5, 0, 2><<<dim3(4, 128), blk, 0, stream>>>(
            SH, nullptr, hw + HMSGW2 + ii * 262144, nullptr, bf + FBE2 + ii * 1024,
            nullptr, nullptr, nullptr, nullptr, P, Hn, 512, 768, 0, flag);
        // E2b: P = sigmoid(hid[:,512:768] @ attW2 + b2) * P
        hgemm_k<EPI_SIGMUL, 5, 0, 2><<<dim3(4, 128), blk, 0, stream>>>(
            SH + 512, nullptr, hw + HATTW2 + ii * 131072, nullptr,
            bf + FBE2 + ii * 1024 + 512, P, nullptr, nullptr, nullptr,
            P, Hn, 256, 768, 0, flag);
        // GRU, 2 chunks of 8192
        for (int cdx = 0; cdx < 2; ++cdx) {
          f16* Pc = P + (size_t)cdx * RCG * 512;
          float* str = state + ((size_t)r * Bn + cdx * RCG) * 512;
          hgemm_k<EPI_SIG, 6, 1, 2><<<dim3(8, 64), blk, 0, stream>>>(
              Pc, str, Wih, Whh, bgrz, nullptr, nullptr, nullptr, nullptr,
              RZ, 1024, 1024, 512, 0, flag);
          hgemm_k<EPI_NONE, 0, 0, 2><<<dim3(4, 64), blk, 0, stream>>>(
              str, nullptr, Whn, nullptr, bhhn, nullptr, nullptr, nullptr,
              nullptr, HN, Hn, 512, 512, 0, flag);
          hgemm_k<EPI_GRU, 5, 0, 0><<<dim3(4, 64), blk, 0, stream>>>(
              Pc, nullptr, Win, nullptr, bihn, RZ, HN, nullptr, nullptr,
              str, Hn, 512, 512, 0, flag);
        }
      }
      // r=0 (A nodes): agg==0
      for (int cdx = 0; cdx < 2; ++cdx) {
        float* str = state + ((size_t)cdx * RCG) * 512;
        hgemm_k<EPI_SIG, 0, 0, 2><<<dim3(8, 64), blk, 0, stream>>>(
            str, nullptr, Whh, nullptr, bgrz, nullptr, nullptr, nullptr,
            nullptr, RZ, 1024, 512, 512, 0, flag);
        hgemm_k<EPI_NONE, 0, 0, 2><<<dim3(4, 64), blk, 0, stream>>>(
            str, nullptr, Whn, nullptr, bhhn, nullptr, nullptr, nullptr,
            nullptr, HN, Hn, 512, 512, 0, flag);
        gate0_k<<<dim3(RCG / 2), blk, 0, stream>>>(RZ, HN, bihn, str);
      }
    }
  }

  // ---- head ----
  hdiff_k<<<dim3(Bn), dim3(128), 0, stream>>>(state, SH);
  hgemm_k<EPI_RELU, 5, 0, 2><<<dim3(4, 128), blk, 0, stream>>>(
      SH, nullptr, hw + HHW1, nullptr, bf + FHB1, nullptr, nullptr, nullptr,
      nullptr, P, Hn, 512, 512, 0, flag);
  head2_k<<<dim3(Bn / 8), blk, 0, stream>>>(P, d_in[24], d_in[25], d_out, flag);
}

// Round 8
// 3431.070 us; speedup vs baseline: 12.5936x; 1.4726x over previous
//
#include <hip/hip_runtime.h>
#include <math.h>

// GRANCascadingPredictor — round 8: fp16 state + XCD swizzle + merged grids.
//
// R7 counters: E1 GEMM latency-bound (MfmaUtil 5.7%, VALU 5.9%, Occ 25%,
// HBM 35%) with 3x HBM over-fetch (207MB vs 67MB state) — cross-XCD L2
// duplicate misses + 3-blocks/CU grids. Fixes:
//  * state fp16 (64MB): halves state traffic; GRU carried-s rounding is
//    self-damping (z~0.5). R7 already fed fp16 state into every MFMA.
//  * XCD swizzle: 1D grid, xcd=bid&7 owns a row band for all col-blocks ->
//    each A-tile hits one L2 once.
//  * P for all 3Bn edges precomputed (48MB); E-phase 2x1.5Bn chunks
//    (1152-block grids, per-type bias via (rowOff+row0)>>14); GRU 4xBn
//    chunks (1024-block RZ).
// ws: flag 256 | bias 64KB | hw 10.6MB | P 48MB | S 48MB | state 64MB
//     = 178.6MB < 189.18MB proven.

#define Bn 16384
#define Hn 512
#define Dn 256
#define Tn 768

#define EPI_NONE 0
#define EPI_RELU 1
#define EPI_SIG 2
#define EPI_SIGMUL 3
#define EPI_RELUGATHER 4
#define EPI_GRU 5

typedef unsigned short bfu;
typedef _Float16 f16;
typedef f16 h4 __attribute__((ext_vector_type(4)));
typedef f16 half8 __attribute__((ext_vector_type(8)));
typedef float floatx4 __attribute__((ext_vector_type(4)));

// fp16 weight arena offsets (halves)
#define HTEXTW 0
#define HPROJW 196608
#define HHW1 327680
#define HWE1 589824
#define HMSGW2 1376256
#define HATTW2 1900544
#define HWIH 2162688
#define HWHH 3735552
#define HTOTAL 5308416
// fp32 bias arena offsets (floats)
#define FTEXTB 0
#define FPROJB 256
#define FHB1 768
#define FGBIH 1280
#define FGBHH 4352
#define FBGRZ 7424
#define FBE1 9472
#define FBE2 14080

__device__ __forceinline__ float sigf(float x) { return 1.f / (1.f + expf(-x)); }

__device__ __forceinline__ float b2f(bfu v) {
  union { unsigned q; float f; } c;
  c.q = (unsigned)v << 16;
  return c.f;
}
__device__ __forceinline__ float4 bf4(uint2 u) {
  union { unsigned q; float f; } c;
  float4 r;
  c.q = u.x << 16;          r.x = c.f;
  c.q = u.x & 0xFFFF0000u;  r.y = c.f;
  c.q = u.y << 16;          r.z = c.f;
  c.q = u.y & 0xFFFF0000u;  r.w = c.f;
  return r;
}
__device__ __forceinline__ unsigned f2bu(float x) {
  union { float f; unsigned u; } c;
  c.f = x;
  return (c.u + 0x7FFFu + ((c.u >> 16) & 1u)) >> 16;
}
__device__ __forceinline__ float4 h2f4(h4 h) {
  return make_float4((float)h.x, (float)h.y, (float)h.z, (float)h.w);
}
__device__ __forceinline__ h4 f2h4c(float4 v) {
  h4 r;
  r.x = (f16)v.x; r.y = (f16)v.y; r.z = (f16)v.z; r.w = (f16)v.w;
  return r;
}
__device__ __forceinline__ half8 ff2h8(float4 a, float4 b) {
  half8 r;
  r[0] = (f16)a.x; r[1] = (f16)a.y; r[2] = (f16)a.z; r[3] = (f16)a.w;
  r[4] = (f16)b.x; r[5] = (f16)b.y; r[6] = (f16)b.z; r[7] = (f16)b.w;
  return r;
}
__device__ __forceinline__ half8 bf2h8(uint4 u) {
  uint2 lo; lo.x = u.x; lo.y = u.y;
  uint2 hi; hi.x = u.z; hi.y = u.w;
  return ff2h8(bf4(lo), bf4(hi));
}

__global__ void detect_k(const unsigned* __restrict__ p, int* __restrict__ flag) {
  __shared__ float red[256];
  const int t = threadIdx.x;
  union { unsigned q; float f; } c;
  c.q = p[t] << 16;
  float m = fabsf(c.f);
  if (!(m == m)) m = 1e30f;
  red[t] = m;
  __syncthreads();
  for (int s = 128; s > 0; s >>= 1) {
    if (t < s) red[t] = fmaxf(red[t], red[t + s]);
    __syncthreads();
  }
  if (t == 0) flag[0] = (red[0] < 1e3f) ? 1 : 0;
}

__device__ __forceinline__ float cvld(const void* p, size_t i, int fl) {
  return fl ? b2f(((const bfu*)p)[i]) : ((const float*)p)[i];
}

__global__ void convF_k(const void* __restrict__ src, size_t off, float* __restrict__ dst,
                        int n, const int* __restrict__ flagp) {
  const int i = blockIdx.x * 256 + threadIdx.x;
  if (i < n) dst[i] = cvld(src, off + i, flagp[0]);
}
__global__ void convH_k(const void* __restrict__ src, size_t off, f16* __restrict__ dst,
                        int n, const int* __restrict__ flagp) {
  const int i = blockIdx.x * 256 + threadIdx.x;
  if (i < n) dst[i] = (f16)cvld(src, off + i, flagp[0]);
}
__global__ void convT_k(const void* __restrict__ src, size_t off, f16* __restrict__ dst,
                        int K, int N, const int* __restrict__ flagp) {
  __shared__ f16 tile[32][33];
  const int t = threadIdx.x;
  const int c = t & 31, r0 = t >> 5;
  const int kb = blockIdx.y * 32, nb = blockIdx.x * 32;
  const int fl = flagp[0];
#pragma unroll
  for (int i = 0; i < 4; ++i)
    tile[r0 + i * 8][c] = (f16)cvld(src, off + (size_t)(kb + r0 + i * 8) * N + nb + c, fl);
  __syncthreads();
#pragma unroll
  for (int i = 0; i < 4; ++i)
    dst[(size_t)(nb + r0 + i * 8) * K + kb + c] = tile[c][r0 + i * 8];
}
__global__ void addv_k(const float* __restrict__ a, const float* __restrict__ b,
                       float* __restrict__ o, int n) {
  const int i = blockIdx.x * 256 + threadIdx.x;
  if (i < n) o[i] = a[i] + b[i];
}
__global__ void btype_k(const void* __restrict__ b, size_t bOff,
                        const void* __restrict__ wr, size_t wrOff,
                        float* __restrict__ dst, int N, int dstStride,
                        const int* __restrict__ flagp) {
  const int i = blockIdx.x * 256 + threadIdx.x;
  const int fl = flagp[0];
  if (i < 3 * N) {
    const int t = i / N, n = i % N;
    dst[(size_t)t * dstStride + n] = cvld(b, bOff + n, fl) + cvld(wr, wrOff + i, fl);
  }
}
__global__ void gather_k(const int* __restrict__ ids, const void* __restrict__ emb,
                         f16* __restrict__ Xc, const int* __restrict__ flagp) {
  const int r = blockIdx.x, t = threadIdx.x;
  const int id = ids[r];
  float4 v;
  if (flagp[0])
    v = bf4(((const uint2*)((const bfu*)emb + (size_t)id * Dn))[t]);
  else
    v = ((const float4*)((const float*)emb + (size_t)id * Dn))[t];
  ((h4*)(Xc + (size_t)r * Dn))[t] = f2h4c(v);
}

// C[M,N] = epi(A @ W + bias), MFMA 16x16x32, 128x128 tile, 4 waves 2x2.
// 1D grid = nCols*nRows, XCD-swizzled: xcd=bid&7 owns rows band for all cols.
// AM: 1=A flag-dtyped global rows rowOff+row; 2=A row e=rowOff+row ->
//     state[src(e)]-state[e+Bn] (fp16, stride 512); 5=A fp16 (aStride);
//     6=A=[P fp16 | state fp16], k<512->Ap else Ap2 (both stride 512).
// BM: 0=Wt[N][K]; 1=k<512->Wt[n][k] else Wt2[n][k-512] (stride 512).
// CT: 0=C fp32; 2=C fp16. BTY: bias += ((rowOff+row0)>>14)*768.
// EPI_SIG: sigmoid. EPI_SIGMUL: sigf(x)*ex1[row*N+col] (fp16, may alias C).
// EPI_RELUGATHER: relu(x)+gtab[gidx[rowOff+row]*N+col] (flag dtype).
// EPI_GRU: r,z=ex1[row*1024+{col,512+col}], hn=ex2[row*512+col], C=state fp16
//          in-place: s=(float)C; C=(1-z)*tanh(x+r*hn)+z*s.
template <int EPI, int AM, int BM, int CT, int BTY>
__global__ __launch_bounds__(256, 2) void hgemm_k(
    const void* __restrict__ Ap, const void* __restrict__ Ap2,
    const f16* __restrict__ Wt, const f16* __restrict__ Wt2,
    const float* __restrict__ bias,
    const f16* __restrict__ ex1, const f16* __restrict__ ex2,
    const int* __restrict__ gidx, const void* __restrict__ gtab,
    void* __restrict__ C, int N, int K, int aStride, int rowOff, int nRows,
    const int* __restrict__ flagp) {
  __shared__ __align__(16) f16 As[128][40];
  __shared__ __align__(16) f16 Bs[128][40];
  const int t = threadIdx.x;
  // XCD swizzle (nRows % 8 == 0)
  const int bid = blockIdx.x;
  const int rowsPerX = nRows >> 3;
  const int slot = bid >> 3;
  const int row0 = ((bid & 7) * rowsPerX + slot % rowsPerX) * 128;
  const int col0 = (slot / rowsPerX) * 128;
  const int lane = t & 63;
  const int wv = t >> 6;
  const int wm = wv >> 1, wn = wv & 1;
  const int l16 = lane & 15, quad = lane >> 4;
  const int arow = t & 127;
  const int ak0 = (t >> 7) * 8;
  const int fl = (AM == 1 || EPI == EPI_RELUGATHER) ? flagp[0] : 0;

  floatx4 acc[4][4];
#pragma unroll
  for (int mi = 0; mi < 4; ++mi)
#pragma unroll
    for (int ni = 0; ni < 4; ++ni) acc[mi][ni] = (floatx4){0.f, 0.f, 0.f, 0.f};

  auto fetchA = [&](int kk, int seg) -> half8 {
    const int k = kk + ak0 + seg * 16;
    const int m = row0 + arow;
    if (AM == 5) {
      return *(const half8*)((const f16*)Ap + (size_t)m * aStride + k);
    } else if (AM == 1) {
      const size_t o = (size_t)(rowOff + m) * aStride + k;
      if (fl) return bf2h8(*(const uint4*)((const bfu*)Ap + o));
      const float* ap = (const float*)Ap + o;
      return ff2h8(*(const float4*)ap, *(const float4*)(ap + 4));
    } else if (AM == 6) {
      if (k < 512) return *(const half8*)((const f16*)Ap + (size_t)m * 512 + k);
      return *(const half8*)((const f16*)Ap2 + (size_t)m * 512 + (k - 512));
    } else {  // AM == 2: state-diff rows, state fp16
      const int e = rowOff + m;
      const int s = (e < 2 * Bn) ? e : e - Bn;
      const f16* st = (const f16*)Ap;
      half8 x = *(const half8*)(st + (size_t)s * 512 + k);
      half8 y = *(const half8*)(st + (size_t)(e + Bn) * 512 + k);
      return x - y;
    }
  };
  auto fetchB = [&](int kk, int seg) -> half8 {
    const int k = kk + ak0 + seg * 16;
    const int n = col0 + arow;
    if (BM == 0) return *(const half8*)(Wt + (size_t)n * K + k);
    if (k < 512) return *(const half8*)(Wt + (size_t)n * 512 + k);
    return *(const half8*)(Wt2 + (size_t)n * 512 + k - 512);
  };

  half8 pa0 = fetchA(0, 0), pa1 = fetchA(0, 1);
  half8 pb0 = fetchB(0, 0), pb1 = fetchB(0, 1);

  int kt = 0;
  while (true) {
    __syncthreads();
    *(half8*)&As[arow][ak0] = pa0;
    *(half8*)&As[arow][ak0 + 16] = pa1;
    *(half8*)&Bs[arow][ak0] = pb0;
    *(half8*)&Bs[arow][ak0 + 16] = pb1;
    __syncthreads();
    const int kn = kt + 32;
    if (kn < K) {
      pa0 = fetchA(kn, 0); pa1 = fetchA(kn, 1);
      pb0 = fetchB(kn, 0); pb1 = fetchB(kn, 1);
    }
    half8 a8[4], b8[4];
#pragma unroll
    for (int mi = 0; mi < 4; ++mi)
      a8[mi] = *(const half8*)&As[wm * 64 + mi * 16 + l16][quad * 8];
#pragma unroll
    for (int ni = 0; ni < 4; ++ni)
      b8[ni] = *(const half8*)&Bs[wn * 64 + ni * 16 + l16][quad * 8];
#pragma unroll
    for (int mi = 0; mi < 4; ++mi)
#pragma unroll
      for (int ni = 0; ni < 4; ++ni)
        acc[mi][ni] = __builtin_amdgcn_mfma_f32_16x16x32_f16(a8[mi], b8[ni],
                                                             acc[mi][ni], 0, 0, 0);
    if (kn >= K) break;
    kt = kn;
  }

  const float* bp = bias;
  if (BTY) bp = bias + ((rowOff + row0) >> 14) * 768;
  const int colBase = col0 + wn * 64;
  const int rowBase = row0 + wm * 64;
#pragma unroll
  for (int mi = 0; mi < 4; ++mi) {
    const int r0r = rowBase + mi * 16 + quad * 4;
#pragma unroll
    for (int ni = 0; ni < 4; ++ni) {
      const int col = colBase + ni * 16 + l16;
      const float bb = bp[col];
      floatx4 v = acc[mi][ni];
#pragma unroll
      for (int rg = 0; rg < 4; ++rg) {
        const int row = r0r + rg;
        float x = v[rg] + bb;
        if (EPI == EPI_RELU || EPI == EPI_RELUGATHER) x = fmaxf(x, 0.f);
        if (EPI == EPI_SIG) x = sigf(x);
        if (EPI == EPI_SIGMUL)
          x = sigf(x) * (float)ex1[(size_t)row * N + col];
        if (EPI == EPI_RELUGATHER) {
          const int grow = gidx[rowOff + row];
          x += fl ? b2f(((const bfu*)gtab)[(size_t)grow * N + col])
                  : ((const float*)gtab)[(size_t)grow * N + col];
        }
        if (EPI == EPI_GRU) {
          const float r_ = (float)ex1[(size_t)row * 1024 + col];
          const float z_ = (float)ex1[(size_t)row * 1024 + 512 + col];
          const float hn = (float)ex2[(size_t)row * 512 + col];
          f16* cf = (f16*)C + (size_t)row * 512 + col;
          const float s = (float)*cf;
          const float n_ = tanhf(x + r_ * hn);
          *cf = (f16)((1.f - z_) * n_ + z_ * s);
        } else if (CT == 0) {
          ((float*)C)[(size_t)row * N + col] = x;
        } else {
          ((f16*)C)[(size_t)row * N + col] = (f16)x;
        }
      }
    }
  }
}

// r=0 (A nodes, agg==0): i_n = bih_n; state fp16 updated in place.
__global__ void gate0_k(const f16* __restrict__ RZ, const f16* __restrict__ HN,
                        const float* __restrict__ bihn, f16* __restrict__ st) {
  const int idx = blockIdx.x * blockDim.x + threadIdx.x;
  const int m = idx >> 7;
  const int c = (idx & 127) << 2;
  float4 r4 = h2f4(*(const h4*)(RZ + (size_t)m * 1024 + c));
  float4 z4 = h2f4(*(const h4*)(RZ + (size_t)m * 1024 + 512 + c));
  float4 hn = h2f4(*(const h4*)(HN + (size_t)m * 512 + c));
  float4 b4 = *(const float4*)(bihn + c);
  f16* sp = st + (size_t)m * 512 + c;
  float4 s = h2f4(*(const h4*)sp);
  float4 o;
  float n_;
  n_ = tanhf(b4.x + r4.x * hn.x); o.x = (1.f - z4.x) * n_ + z4.x * s.x;
  n_ = tanhf(b4.y + r4.y * hn.y); o.y = (1.f - z4.y) * n_ + z4.y * s.y;
  n_ = tanhf(b4.z + r4.z * hn.z); o.z = (1.f - z4.z) * n_ + z4.z * s.z;
  n_ = tanhf(b4.w + r4.w * hn.w); o.w = (1.f - z4.w) * n_ + z4.w * s.w;
  *(h4*)sp = f2h4c(o);
}

__global__ void hdiff_k(const f16* __restrict__ st, f16* __restrict__ Dh) {
  const int m = blockIdx.x, t = threadIdx.x;  // 64 thr x half8
  half8 a = ((const half8*)(st + (size_t)m * Hn))[t];
  half8 b = ((const half8*)(st + (size_t)(2 * Bn + m) * Hn))[t];
  ((half8*)(Dh + (size_t)m * Hn))[t] = a - b;
}

// packed-fp16 relu (sign-bit mask, positions identical to bf16)
__global__ void relu_h_k(uint4* __restrict__ p, long n) {
  long i = (long)blockIdx.x * blockDim.x + threadIdx.x;
  if (i < n) {
    uint4 v = p[i];
    v.x = ((v.x & 0x8000u) ? 0u : (v.x & 0xFFFFu)) |
          ((v.x & 0x80000000u) ? 0u : (v.x & 0xFFFF0000u));
    v.y = ((v.y & 0x8000u) ? 0u : (v.y & 0xFFFFu)) |
          ((v.y & 0x80000000u) ? 0u : (v.y & 0xFFFF0000u));
    v.z = ((v.z & 0x8000u) ? 0u : (v.z & 0xFFFFu)) |
          ((v.z & 0x80000000u) ? 0u : (v.z & 0xFFFF0000u));
    v.w = ((v.w & 0x8000u) ? 0u : (v.w & 0xFFFFu)) |
          ((v.w & 0x80000000u) ? 0u : (v.w & 0xFFFF0000u));
    p[i] = v;
  }
}

__global__ void head2_k(const f16* __restrict__ Hh, const void* __restrict__ W2,
                        const void* __restrict__ b2, void* __restrict__ out,
                        const int* __restrict__ flagp) {
  __shared__ __align__(16) float Ws[64][32];
  __shared__ __align__(16) float As2[8][64];
  const int t = threadIdx.x;
  const int r0 = blockIdx.x * 8;
  const int lr = t >> 5, c = t & 31;
  const int fl = flagp[0];
  float acc = 0.f;
  for (int kc = 0; kc < 512; kc += 64) {
    __syncthreads();
    if (fl) {
      uint4 u = ((const uint4*)((const bfu*)W2 + (size_t)kc * 32))[t];
      uint2 lo; lo.x = u.x; lo.y = u.y;
      uint2 hi; hi.x = u.z; hi.y = u.w;
      ((float4*)&Ws[0][0])[t * 2] = bf4(lo);
      ((float4*)&Ws[0][0])[t * 2 + 1] = bf4(hi);
    } else {
      const float4* src = (const float4*)((const float*)W2 + (size_t)kc * 32);
      ((float4*)&Ws[0][0])[t * 2] = src[t * 2];
      ((float4*)&Ws[0][0])[t * 2 + 1] = src[t * 2 + 1];
    }
    {
      const int i = t * 2, rr = i >> 6, cc = i & 63;
      const f16* hp = Hh + (size_t)(r0 + rr) * 512 + kc + cc;
      As2[rr][cc] = (float)hp[0];
      As2[rr][cc + 1] = (float)hp[1];
    }
    __syncthreads();
#pragma unroll
    for (int k = 0; k < 64; ++k) acc = fmaf(As2[lr][k], Ws[k][c], acc);
  }
  const float bb = fl ? b2f(((const bfu*)b2)[c]) : ((const float*)b2)[c];
  const float r = acc + bb;
  const size_t o = (size_t)(r0 + lr) * 32 + c;
  if (fl) ((bfu*)out)[o] = (bfu)f2bu(r);
  else ((float*)out)[o] = r;
}

extern "C" void kernel_launch(void* const* d_in, const int* in_sizes, int n_in,
                              void* d_out, int out_size, void* d_ws, size_t ws_size,
                              hipStream_t stream) {
  const int* a_ids = (const int*)d_in[0];
  const int* event_ids = (const int*)d_in[1];
  const int* b_ids = (const int*)d_in[2];
  const int* c_ids = (const int*)d_in[3];
  const void* text_ab = d_in[4];
  const void* ent_emb = d_in[5];

  char* w = (char*)d_ws;
  int* flag = (int*)w;   w += 256;
  float* bf = (float*)w; w += 65536;
  f16* hw = (f16*)w;     w += (size_t)HTOTAL * 2;       // 10.6 MB
  f16* P = (f16*)w;      w += (size_t)3 * Bn * 512 * 2; // 48 MB
  f16* S = (f16*)w;      w += (size_t)50331648;         // 48 MB scratch
  f16* state = (f16*)w;                                 // 64 MB
  f16* RZ = S;                          // Bn x 1024 (32 MB)
  f16* HN = S + (size_t)Bn * 1024;      // Bn x 512  (16 MB)
  const dim3 blk(256);

  detect_k<<<dim3(1), blk, 0, stream>>>((const unsigned*)ent_emb, flag);

  struct CF { int idx; size_t off; int dst; int n; };
  const CF cfs[9] = {{7, 0, FTEXTB, 256},   {9, 0, FPROJB, 512},
                     {23, 0, FHB1, 512},    {20, 0, FGBIH, 3072},
                     {21, 0, FGBHH, 3072},  {13, 0, FBE2, 512},
                     {17, 0, FBE2 + 512, 512}, {13, 512, FBE2 + 1024, 512},
                     {17, 512, FBE2 + 1536, 512}};
  for (int i = 0; i < 9; ++i)
    convF_k<<<dim3((cfs[i].n + 255) / 256), blk, 0, stream>>>(
        d_in[cfs[i].idx], cfs[i].off, bf + cfs[i].dst, cfs[i].n, flag);

  convT_k<<<dim3(8, 24), blk, 0, stream>>>(d_in[6], 0, hw + HTEXTW, Tn, Dn, flag);
  convT_k<<<dim3(16, 8), blk, 0, stream>>>(d_in[8], 0, hw + HPROJW, Dn, Hn, flag);
  convT_k<<<dim3(16, 16), blk, 0, stream>>>(d_in[22], 0, hw + HHW1, Hn, Hn, flag);
  for (int ii = 0; ii < 2; ++ii) {
    convT_k<<<dim3(16, 16), blk, 0, stream>>>(
        d_in[10], (size_t)ii * 520 * 512, hw + HWE1 + ii * 393216, Hn, Hn, flag);
    convT_k<<<dim3(8, 16), blk, 0, stream>>>(
        d_in[14], (size_t)ii * 520 * 256, hw + HWE1 + ii * 393216 + 262144, Hn, 256, flag);
    convT_k<<<dim3(16, 16), blk, 0, stream>>>(
        d_in[12], (size_t)ii * 512 * 512, hw + HMSGW2 + ii * 262144, Hn, Hn, flag);
    convT_k<<<dim3(16, 8), blk, 0, stream>>>(
        d_in[16], (size_t)ii * 256 * 512, hw + HATTW2 + ii * 131072, 256, Hn, flag);
    convH_k<<<dim3(3072), blk, 0, stream>>>(
        d_in[18], (size_t)ii * 786432, hw + HWIH + ii * 786432, 786432, flag);
    convH_k<<<dim3(3072), blk, 0, stream>>>(
        d_in[19], (size_t)ii * 786432, hw + HWHH + ii * 786432, 786432, flag);
    addv_k<<<dim3(4), blk, 0, stream>>>(bf + FGBIH + ii * 1536, bf + FGBHH + ii * 1536,
                                        bf + FBGRZ + ii * 1024, 1024);
    btype_k<<<dim3(6), blk, 0, stream>>>(
        d_in[11], (size_t)ii * 512, d_in[10], (size_t)ii * 520 * 512 + 512 * 512,
        bf + FBE1 + ii * 2304, 512, 768, flag);
    btype_k<<<dim3(3), blk, 0, stream>>>(
        d_in[15], (size_t)ii * 256, d_in[14], (size_t)ii * 520 * 256 + 512 * 256,
        bf + FBE1 + ii * 2304 + 512, 256, 768, flag);
  }

  // ---- input phase: state(fp16) = relu(proj(X)) ----
  f16* Xc = S;
  const int* gids[3] = {a_ids, b_ids, c_ids};
  const size_t gdst[3] = {0, (size_t)2 * Bn, (size_t)3 * Bn};
  for (int g = 0; g < 3; ++g) {
    gather_k<<<dim3(Bn), dim3(64), 0, stream>>>(gids[g], ent_emb, Xc, flag);
    hgemm_k<EPI_RELU, 5, 0, 2, 0><<<dim3(4 * 128), blk, 0, stream>>>(
        Xc, nullptr, hw + HPROJW, nullptr, bf + FPROJB, nullptr, nullptr,
        nullptr, nullptr, state + gdst[g] * 512, Hn, Dn, Dn, 0, 128, flag);
  }
  hgemm_k<EPI_RELUGATHER, 1, 0, 2, 0><<<dim3(2 * 128), blk, 0, stream>>>(
      text_ab, nullptr, hw + HTEXTW, nullptr, bf + FTEXTB, nullptr, nullptr,
      event_ids, ent_emb, Xc, Dn, Tn, Tn, 0, 128, flag);
  hgemm_k<EPI_RELU, 5, 0, 2, 0><<<dim3(4 * 128), blk, 0, stream>>>(
      Xc, nullptr, hw + HPROJW, nullptr, bf + FPROJB, nullptr, nullptr,
      nullptr, nullptr, state + (size_t)Bn * 512, Hn, Dn, Dn, 0, 128, flag);

  // ---- propagation ----
  for (int ii = 0; ii < 2; ++ii) {
    if (ii > 0)
      relu_h_k<<<dim3(16384), blk, 0, stream>>>((uint4*)state,
                                                (long)4 * Bn * Hn * 2 / 16);
    const f16* Wih = hw + HWIH + (size_t)ii * 786432;
    const f16* Whh = hw + HWHH + (size_t)ii * 786432;
    const f16* Win = Wih + (size_t)1024 * 512;
    const f16* Whn = Whh + (size_t)1024 * 512;
    const float* bgrz = bf + FBGRZ + ii * 1024;
    const float* bihn = bf + FGBIH + ii * 1536 + 1024;
    const float* bhhn = bf + FGBHH + ii * 1536 + 1024;
    for (int p = 0; p < 2; ++p) {
      // E-phase: all 3Bn edges -> P, in 2 chunks of 1.5Bn rows
      for (int c = 0; c < 2; ++c) {
        const int e0 = c * 24576;
        f16* hid = S;  // 1.5Bn x 768 = 36 MB
        hgemm_k<EPI_RELU, 2, 0, 2, 1><<<dim3(6 * 192), blk, 0, stream>>>(
            state, nullptr, hw + HWE1 + ii * 393216, nullptr,
            bf + FBE1 + ii * 2304, nullptr, nullptr, nullptr, nullptr,
            hid, 768, Hn, 512, e0, 192, flag);
        hgemm_k<EPI_NONE, 5, 0, 2, 0><<<dim3(4 * 192), blk, 0, stream>>>(
            hid, nullptr, hw + HMSGW2 + ii * 262144, nullptr, bf + FBE2 + ii * 1024,
            nullptr, nullptr, nullptr, nullptr, P + (size_t)e0 * 512,
            Hn, 512, 768, 0, 192, flag);
        hgemm_k<EPI_SIGMUL, 5, 0, 2, 0><<<dim3(4 * 192), blk, 0, stream>>>(
            hid + 512, nullptr, hw + HATTW2 + ii * 131072, nullptr,
            bf + FBE2 + ii * 1024 + 512, P + (size_t)e0 * 512, nullptr,
            nullptr, nullptr, P + (size_t)e0 * 512, Hn, 256, 768, 0, 192, flag);
      }
      // GRU: chunks r=1..3 (P-fed), each Bn rows
      for (int r = 1; r <= 3; ++r) {
        f16* Pc = P + (size_t)(r - 1) * Bn * 512;
        f16* str = state + (size_t)r * Bn * 512;
        hgemm_k<EPI_SIG, 6, 1, 2, 0><<<dim3(8 * 128), blk, 0, stream>>>(
            Pc, str, Wih, Whh, bgrz, nullptr, nullptr, nullptr, nullptr,
            RZ, 1024, 1024, 512, 0, 128, flag);
        hgemm_k<EPI_NONE, 5, 0, 2, 0><<<dim3(4 * 128), blk, 0, stream>>>(
            str, nullptr, Whn, nullptr, bhhn, nullptr, nullptr, nullptr,
            nullptr, HN, Hn, 512, 512, 0, 128, flag);
        hgemm_k<EPI_GRU, 5, 0, 0, 0><<<dim3(4 * 128), blk, 0, stream>>>(
            Pc, nullptr, Win, nullptr, bihn, RZ, HN, nullptr, nullptr,
            str, Hn, 512, 512, 0, 128, flag);
      }
      // r=0 (A nodes, agg==0)
      hgemm_k<EPI_SIG, 5, 0, 2, 0><<<dim3(8 * 128), blk, 0, stream>>>(
          state, nullptr, Whh, nullptr, bgrz, nullptr, nullptr, nullptr,
          nullptr, RZ, 1024, 512, 512, 0, 128, flag);
      hgemm_k<EPI_NONE, 5, 0, 2, 0><<<dim3(4 * 128), blk, 0, stream>>>(
          state, nullptr, Whn, nullptr, bhhn, nullptr, nullptr, nullptr,
          nullptr, HN, Hn, 512, 512, 0, 128, flag);
      gate0_k<<<dim3(8192), blk, 0, stream>>>(RZ, HN, bihn, state);
    }
  }

  // ---- head ----
  hdiff_k<<<dim3(Bn), dim3(64), 0, stream>>>(state, S);
  hgemm_k<EPI_RELU, 5, 0, 2, 0><<<dim3(4 * 128), blk, 0, stream>>>(
      S, nullptr, hw + HHW1, nullptr, bf + FHB1, nullptr, nullptr, nullptr,
      nullptr, P, Hn, 512, 512, 0, 128, flag);
  head2_k<<<dim3(Bn / 8), blk, 0, stream>>>(P, d_in[24], d_in[25], d_out, flag);
}